// Round 1
// baseline (17331.197 us; speedup 1.0000x reference)
//
#include <hip/hip_runtime.h>
#include <cstddef>

// Problem constants (fixed by the reference)
#define DEPTH  8
#define DIMM   1024
#define DI     2048      // d_inner
#define NST    16        // d_state
#define DCONVK 4
#define DTRANK 64
#define BB     2
#define LL     2048
#define MM     (BB*LL)   // 4096 rows

// ---------------- GEMM: C[M,N] = A[M,K] (lda) * W[N,K]^T ----------------
// fp32, 128x128 block tile, BK=16, 256 threads, 8x8 accum/thread.
// Half-tile split (ty*4+i and 64+ty*4+i) keeps LDS reads at stride-4 ->
// <=2-way bank aliasing (free on gfx950 per m136).
#define TBM 128
#define TBN 128
#define TBK 16

__global__ __launch_bounds__(256) void gemm_nt(const float* __restrict__ A, int lda,
                                               const float* __restrict__ W,
                                               float* __restrict__ C,
                                               int M, int N, int K) {
  __shared__ float As[TBK][TBM];
  __shared__ float Ws[TBK][TBN];
  const int t  = threadIdx.x;
  const int tx = t & 15;
  const int ty = (t >> 4) & 15;
  const int m0 = blockIdx.y * TBM;
  const int n0 = blockIdx.x * TBN;

  float acc[8][8];
#pragma unroll
  for (int i = 0; i < 8; ++i)
#pragma unroll
    for (int j = 0; j < 8; ++j) acc[i][j] = 0.f;

  for (int k0 = 0; k0 < K; k0 += TBK) {
#pragma unroll
    for (int j = 0; j < 2; ++j) {
      int e  = t + j * 256;        // 512 float4 slots per tile
      int r  = e >> 2;             // 0..127
      int cq = (e & 3) << 2;       // 0,4,8,12
      const float* ap = A + (size_t)(m0 + r) * lda + (k0 + cq);
      float4 v = *(const float4*)ap;
      As[cq+0][r] = v.x; As[cq+1][r] = v.y; As[cq+2][r] = v.z; As[cq+3][r] = v.w;
      int n = n0 + r;
      float4 w;
      if (n < N) w = *(const float4*)(W + (size_t)n * K + (k0 + cq));
      else { w.x = 0.f; w.y = 0.f; w.z = 0.f; w.w = 0.f; }
      Ws[cq+0][r] = w.x; Ws[cq+1][r] = w.y; Ws[cq+2][r] = w.z; Ws[cq+3][r] = w.w;
    }
    __syncthreads();
#pragma unroll
    for (int kk = 0; kk < TBK; ++kk) {
      float a[8], b[8];
#pragma unroll
      for (int i = 0; i < 4; ++i) { a[i] = As[kk][ty*4 + i]; a[i+4] = As[kk][64 + ty*4 + i]; }
#pragma unroll
      for (int j = 0; j < 4; ++j) { b[j] = Ws[kk][tx*4 + j]; b[j+4] = Ws[kk][64 + tx*4 + j]; }
#pragma unroll
      for (int i = 0; i < 8; ++i)
#pragma unroll
        for (int j = 0; j < 8; ++j) acc[i][j] += a[i] * b[j];
    }
    __syncthreads();
  }

#pragma unroll
  for (int i = 0; i < 8; ++i) {
    int m = m0 + ((i < 4) ? (ty*4 + i) : (64 + ty*4 + (i - 4)));
#pragma unroll
    for (int jh = 0; jh < 2; ++jh) {
      int n = n0 + jh*64 + tx*4;
      if (n < N) {   // N is always a multiple of 4, so full float4 is safe
        float4 v;
        v.x = acc[i][jh*4+0]; v.y = acc[i][jh*4+1];
        v.z = acc[i][jh*4+2]; v.w = acc[i][jh*4+3];
        *(float4*)(C + (size_t)m * N + n) = v;
      }
    }
  }
}

// ---------------- depthwise causal conv1d + SiLU ----------------
// xz: [B,L,2*DI] (xs = cols 0..DI-1). out xc: [B,L,DI]
__global__ __launch_bounds__(256) void conv_silu_k(const float* __restrict__ xz,
                                                   const float* __restrict__ cw,
                                                   const float* __restrict__ cb,
                                                   float* __restrict__ xc) {
  int idx = blockIdx.x * 256 + threadIdx.x;   // over MM*DI
  int c  = idx & (DI - 1);
  int bl = idx >> 11;
  int l  = bl & (LL - 1);
  float acc = cb[c];
#pragma unroll
  for (int k = 0; k < DCONVK; ++k) {
    int ls = l - (DCONVK - 1) + k;
    if (ls >= 0)
      acc += xz[(size_t)(bl - (DCONVK - 1) + k) * (2*DI) + c] * cw[c*DCONVK + k];
  }
  xc[idx] = acc / (1.f + expf(-acc));   // silu
}

// ---------------- bias + softplus (in-place on delta) ----------------
__global__ __launch_bounds__(256) void bias_softplus_k(float* __restrict__ delta,
                                                       const float* __restrict__ bdt) {
  int idx = blockIdx.x * 256 + threadIdx.x;
  int c = idx & (DI - 1);
  float x = delta[idx] + bdt[c];
  delta[idx] = fmaxf(x, 0.f) + log1pf(expf(-fabsf(x)));  // stable softplus
}

// ---------------- selective scan ----------------
// 1 thread per (b,d,n); 16 lanes per channel; y written in-place over delta.
// In-wave ordering makes the read-then-write of dy[bl*DI+d] hazard-free.
__global__ __launch_bounds__(256) void scan_k(float* dy,                       // in: delta, out: y
                                              const float* __restrict__ xc,
                                              const float* __restrict__ xdbl, // [MM,96]: dt|B|C
                                              const float* __restrict__ A_log) {
  int t  = threadIdx.x;
  int n  = t & (NST - 1);
  int ch = blockIdx.x * 16 + (t >> 4);   // 0..B*DI-1
  int b  = ch >> 11;
  int d  = ch & (DI - 1);
  float Av = -expf(A_log[d * NST + n]);
  float h = 0.f;
  const size_t chbase = (size_t)b * LL;
  for (int l = 0; l < LL; ++l) {
    size_t bl = chbase + l;
    float dt = dy[bl * DI + d];
    float xt = xc[bl * DI + d];
    float Bt = xdbl[bl * 96 + DTRANK + n];
    float Ct = xdbl[bl * 96 + DTRANK + NST + n];
    h = expf(dt * Av) * h + (dt * xt) * Bt;
    float contrib = h * Ct;
    contrib += __shfl_xor(contrib, 1, 16);
    contrib += __shfl_xor(contrib, 2, 16);
    contrib += __shfl_xor(contrib, 4, 16);
    contrib += __shfl_xor(contrib, 8, 16);
    if (n == 0) dy[bl * DI + d] = contrib;
  }
}

// ---------------- y = (y_scan + xc*D) * silu(z)  (in-place on y) ----------------
__global__ __launch_bounds__(256) void combine_k(float* __restrict__ y,
                                                 const float* __restrict__ xc,
                                                 const float* __restrict__ xz,
                                                 const float* __restrict__ Dp) {
  int idx = blockIdx.x * 256 + threadIdx.x;
  int c  = idx & (DI - 1);
  int bl = idx >> 11;
  float z = xz[(size_t)bl * (2*DI) + DI + c];
  float sz = z / (1.f + expf(-z));
  y[idx] = (y[idx] + xc[idx] * Dp[c]) * sz;
}

// ---------------- RMSNorm over rows of DIMM ----------------
__global__ __launch_bounds__(256) void rmsnorm_k(const float* __restrict__ x,
                                                 const float* __restrict__ w,
                                                 float* __restrict__ o) {
  int row = blockIdx.x;
  const float* xr = x + (size_t)row * DIMM;
  float s = 0.f;
  for (int i = threadIdx.x; i < DIMM; i += 256) { float v = xr[i]; s += v * v; }
#pragma unroll
  for (int off = 32; off > 0; off >>= 1) s += __shfl_xor(s, off, 64);
  __shared__ float red[4];
  if ((threadIdx.x & 63) == 0) red[threadIdx.x >> 6] = s;
  __syncthreads();
  float tot = red[0] + red[1] + red[2] + red[3];
  float scale = rsqrtf(tot * (1.0f / DIMM) + 1e-5f);
  for (int i = threadIdx.x; i < DIMM; i += 256)
    o[(size_t)row * DIMM + i] = xr[i] * scale * w[i];
}

extern "C" void kernel_launch(void* const* d_in, const int* in_sizes, int n_in,
                              void* d_out, int out_size, void* d_ws, size_t ws_size,
                              hipStream_t stream) {
  (void)in_sizes; (void)n_in; (void)out_size; (void)ws_size;
  const float* x_in    = (const float*)d_in[0];
  const float* Wi_all  = (const float*)d_in[1];
  const float* cw_all  = (const float*)d_in[2];
  const float* cb_all  = (const float*)d_in[3];
  const float* Wx_all  = (const float*)d_in[4];
  const float* Wdt_all = (const float*)d_in[5];
  const float* bdt_all = (const float*)d_in[6];
  const float* Alog_all= (const float*)d_in[7];
  const float* D_all   = (const float*)d_in[8];
  const float* Wo_all  = (const float*)d_in[9];
  const float* rw_all  = (const float*)d_in[10];
  float* out = (float*)d_out;

  // Workspace layout (floats); total ~152.6 MB. outtmp reuses xc (xc is dead
  // after combine_k; conv of next layer rewrites it after rmsnorm consumed it).
  float* ws    = (float*)d_ws;
  float* xz    = ws;                          // MM*2*DI  = 16777216
  float* xc    = xz   + (size_t)MM * 2 * DI;  // MM*DI    =  8388608
  float* xdbl  = xc   + (size_t)MM * DI;      // MM*96    =   393216
  float* delta = xdbl + (size_t)MM * 96;      // MM*DI    =  8388608
  float* xbuf  = delta+ (size_t)MM * DI;      // MM*DIMM  =  4194304
  float* outtmp = xc;

  const int EW_GRID = (MM * DI) / 256;        // 32768 blocks

  for (int i = 0; i < DEPTH; ++i) {
    const float* Wi   = Wi_all  + (size_t)i * (2*DI) * DIMM;
    const float* cw   = cw_all  + (size_t)i * DI * DCONVK;
    const float* cb   = cb_all  + (size_t)i * DI;
    const float* Wx   = Wx_all  + (size_t)i * 96 * DI;
    const float* Wdt  = Wdt_all + (size_t)i * DI * DTRANK;
    const float* bdt  = bdt_all + (size_t)i * DI;
    const float* Alog = Alog_all+ (size_t)i * DI * NST;
    const float* Dp   = D_all   + (size_t)i * DI;
    const float* Wo   = Wo_all  + (size_t)i * DIMM * DI;
    const float* rw   = rw_all  + (size_t)i * DIMM;
    const float* xin  = (i == 0) ? x_in : xbuf;
    float* xout = (i == DEPTH - 1) ? out : xbuf;

    // 1) in_proj: xz[MM, 2*DI] = x[MM, DIMM] * Wi[2*DI, DIMM]^T
    gemm_nt<<<dim3((2*DI)/TBN, MM/TBM), 256, 0, stream>>>(xin, DIMM, Wi, xz, MM, 2*DI, DIMM);
    // 2) depthwise causal conv + silu -> xc[MM, DI]
    conv_silu_k<<<EW_GRID, 256, 0, stream>>>(xz, cw, cb, xc);
    // 3) x_proj: xdbl[MM, 96] = xc * Wx^T
    gemm_nt<<<dim3(1, MM/TBM), 256, 0, stream>>>(xc, DI, Wx, xdbl, MM, 96, DI);
    // 4) dt_proj: delta[MM, DI] = xdbl[:, :64] (lda=96) * Wdt^T
    gemm_nt<<<dim3(DI/TBN, MM/TBM), 256, 0, stream>>>(xdbl, 96, Wdt, delta, MM, DI, DTRANK);
    // 5) delta = softplus(delta + bdt)
    bias_softplus_k<<<EW_GRID, 256, 0, stream>>>(delta, bdt);
    // 6) selective scan (y overwrites delta)
    scan_k<<<(BB*DI)/16, 256, 0, stream>>>(delta, xc, xdbl, Alog);
    // 7) y = (y + xc*D) * silu(z)
    combine_k<<<EW_GRID, 256, 0, stream>>>(delta, xc, xz, Dp);
    // 8) out_proj: outtmp[MM, DIMM] = y * Wo^T
    gemm_nt<<<dim3(DIMM/TBN, MM/TBM), 256, 0, stream>>>(delta, DI, Wo, outtmp, MM, DIMM, DI);
    // 9) rmsnorm -> next x (or d_out)
    rmsnorm_k<<<MM, 256, 0, stream>>>(outtmp, rw, xout);
  }
}

// Round 2
// 13436.670 us; speedup vs baseline: 1.2898x; 1.2898x over previous
//
#include <hip/hip_runtime.h>
#include <cstddef>

// Problem constants (fixed by the reference)
#define DEPTH  8
#define DIMM   1024
#define DI     2048      // d_inner
#define NST    16        // d_state
#define DCONVK 4
#define DTRANK 64
#define BB     2
#define LL     2048
#define MM     (BB*LL)   // 4096 rows

// ---------------- GEMM: C[M,N] = A[M,K] (lda) * W[N,K]^T ----------------
#define TBM 128
#define TBN 128
#define TBK 16

__global__ __launch_bounds__(256) void gemm_nt(const float* __restrict__ A, int lda,
                                               const float* __restrict__ W,
                                               float* __restrict__ C,
                                               int M, int N, int K) {
  __shared__ float As[TBK][TBM];
  __shared__ float Ws[TBK][TBN];
  const int t  = threadIdx.x;
  const int tx = t & 15;
  const int ty = (t >> 4) & 15;
  const int m0 = blockIdx.y * TBM;
  const int n0 = blockIdx.x * TBN;

  float acc[8][8];
#pragma unroll
  for (int i = 0; i < 8; ++i)
#pragma unroll
    for (int j = 0; j < 8; ++j) acc[i][j] = 0.f;

  for (int k0 = 0; k0 < K; k0 += TBK) {
#pragma unroll
    for (int j = 0; j < 2; ++j) {
      int e  = t + j * 256;        // 512 float4 slots per tile
      int r  = e >> 2;             // 0..127
      int cq = (e & 3) << 2;       // 0,4,8,12
      const float* ap = A + (size_t)(m0 + r) * lda + (k0 + cq);
      float4 v = *(const float4*)ap;
      As[cq+0][r] = v.x; As[cq+1][r] = v.y; As[cq+2][r] = v.z; As[cq+3][r] = v.w;
      int n = n0 + r;
      float4 w;
      if (n < N) w = *(const float4*)(W + (size_t)n * K + (k0 + cq));
      else { w.x = 0.f; w.y = 0.f; w.z = 0.f; w.w = 0.f; }
      Ws[cq+0][r] = w.x; Ws[cq+1][r] = w.y; Ws[cq+2][r] = w.z; Ws[cq+3][r] = w.w;
    }
    __syncthreads();
#pragma unroll
    for (int kk = 0; kk < TBK; ++kk) {
      float a[8], b[8];
#pragma unroll
      for (int i = 0; i < 4; ++i) { a[i] = As[kk][ty*4 + i]; a[i+4] = As[kk][64 + ty*4 + i]; }
#pragma unroll
      for (int j = 0; j < 4; ++j) { b[j] = Ws[kk][tx*4 + j]; b[j+4] = Ws[kk][64 + tx*4 + j]; }
#pragma unroll
      for (int i = 0; i < 8; ++i)
#pragma unroll
        for (int j = 0; j < 8; ++j) acc[i][j] += a[i] * b[j];
    }
    __syncthreads();
  }

#pragma unroll
  for (int i = 0; i < 8; ++i) {
    int m = m0 + ((i < 4) ? (ty*4 + i) : (64 + ty*4 + (i - 4)));
#pragma unroll
    for (int jh = 0; jh < 2; ++jh) {
      int n = n0 + jh*64 + tx*4;
      if (n < N) {
        float4 v;
        v.x = acc[i][jh*4+0]; v.y = acc[i][jh*4+1];
        v.z = acc[i][jh*4+2]; v.w = acc[i][jh*4+3];
        *(float4*)(C + (size_t)m * N + n) = v;
      }
    }
  }
}

// ---------------- depthwise causal conv1d + SiLU ----------------
__global__ __launch_bounds__(256) void conv_silu_k(const float* __restrict__ xz,
                                                   const float* __restrict__ cw,
                                                   const float* __restrict__ cb,
                                                   float* __restrict__ xc) {
  int idx = blockIdx.x * 256 + threadIdx.x;   // over MM*DI
  int c  = idx & (DI - 1);
  int bl = idx >> 11;
  int l  = bl & (LL - 1);
  float acc = cb[c];
#pragma unroll
  for (int k = 0; k < DCONVK; ++k) {
    int ls = l - (DCONVK - 1) + k;
    if (ls >= 0)
      acc += xz[(size_t)(bl - (DCONVK - 1) + k) * (2*DI) + c] * cw[c*DCONVK + k];
  }
  xc[idx] = acc / (1.f + expf(-acc));   // silu
}

// ---------------- bias + softplus (in-place on delta) ----------------
__global__ __launch_bounds__(256) void bias_softplus_k(float* __restrict__ delta,
                                                       const float* __restrict__ bdt) {
  int idx = blockIdx.x * 256 + threadIdx.x;
  int c = idx & (DI - 1);
  float x = delta[idx] + bdt[c];
  delta[idx] = fmaxf(x, 0.f) + log1pf(expf(-fabsf(x)));  // stable softplus
}

// ---------------- selective scan + gate/combine (fused) ----------------
// 1 thread per (b,d,n); 16 lanes per channel. y written in-place over delta.
// Software-pipelined: group of SU timesteps prefetched into registers one
// group ahead (ping-pong), so cache-miss latency overlaps the h-recurrence.
// Loads are issued in source order BEFORE the group's stores; runtime
// addresses never overlap (store at l, loads at l+SU..), so in-place is safe.
#define SU 8
__global__ __launch_bounds__(256) void scan_k(float* dy,                       // in: delta, out: y_final
                                              const float* __restrict__ xc,
                                              const float* __restrict__ xdbl, // [MM,96]: dt|B|C
                                              const float* __restrict__ A_log,
                                              const float* __restrict__ xz,   // [MM,2*DI] (z = cols DI..)
                                              const float* __restrict__ Dp) {
  const int t  = threadIdx.x;
  const int n  = t & (NST - 1);
  const int ch = blockIdx.x * 16 + (t >> 4);   // 0..B*DI-1
  const int b  = ch >> 11;
  const int d  = ch & (DI - 1);
  const float Av2 = -expf(A_log[d * NST + n]) * 1.44269504088896f; // for exp2f
  const float Dv  = Dp[d];
  float h = 0.f;
  const size_t rowbase = (size_t)b * LL;   // bl = rowbase + l

  float aA[SU], aX[SU], aB[SU], aC[SU], aZ[SU];   // buffer 0
  float bA[SU], bX[SU], bB[SU], bC[SU], bZ[SU];   // buffer 1

#define LOADG(l0, A_, X_, B_, C_, Z_)                                 \
  {                                                                   \
    _Pragma("unroll")                                                 \
    for (int u = 0; u < SU; ++u) {                                    \
      size_t bl = rowbase + (l0) + u;                                 \
      A_[u] = dy  [bl * DI + d];                                      \
      X_[u] = xc  [bl * DI + d];                                      \
      B_[u] = xdbl[bl * 96 + DTRANK + n];                             \
      C_[u] = xdbl[bl * 96 + DTRANK + NST + n];                       \
      Z_[u] = xz  [bl * (2*DI) + DI + d];                             \
    }                                                                 \
  }

#define COMPG(l0, A_, X_, B_, C_, Z_)                                 \
  {                                                                   \
    _Pragma("unroll")                                                 \
    for (int u = 0; u < SU; ++u) {                                    \
      float dt = A_[u];                                               \
      float dA = exp2f(dt * Av2);                                     \
      h = fmaf(dA, h, dt * X_[u] * B_[u]);                            \
      float s = h * C_[u];                                            \
      s += __shfl_xor(s, 1, 16);                                      \
      s += __shfl_xor(s, 2, 16);                                      \
      s += __shfl_xor(s, 4, 16);                                      \
      s += __shfl_xor(s, 8, 16);                                      \
      float z = Z_[u];                                                \
      float yv = (s + X_[u] * Dv) * (z / (1.f + expf(-z)));           \
      if (n == 0) dy[(rowbase + (l0) + u) * DI + d] = yv;             \
    }                                                                 \
  }

  LOADG(0, aA, aX, aB, aC, aZ);                 // prologue
  for (int l0 = 0; l0 < LL; l0 += 2 * SU) {
    LOADG(l0 + SU, bA, bX, bB, bC, bZ);         // prefetch next group
    COMPG(l0, aA, aX, aB, aC, aZ);
    if (l0 + 2 * SU < LL)
      LOADG(l0 + 2 * SU, aA, aX, aB, aC, aZ);   // prefetch next-next
    COMPG(l0 + SU, bA, bX, bB, bC, bZ);
  }
#undef LOADG
#undef COMPG
}

// ---------------- RMSNorm over rows of DIMM ----------------
__global__ __launch_bounds__(256) void rmsnorm_k(const float* __restrict__ x,
                                                 const float* __restrict__ w,
                                                 float* __restrict__ o) {
  int row = blockIdx.x;
  const float* xr = x + (size_t)row * DIMM;
  float s = 0.f;
  for (int i = threadIdx.x; i < DIMM; i += 256) { float v = xr[i]; s += v * v; }
#pragma unroll
  for (int off = 32; off > 0; off >>= 1) s += __shfl_xor(s, off, 64);
  __shared__ float red[4];
  if ((threadIdx.x & 63) == 0) red[threadIdx.x >> 6] = s;
  __syncthreads();
  float tot = red[0] + red[1] + red[2] + red[3];
  float scale = rsqrtf(tot * (1.0f / DIMM) + 1e-5f);
  for (int i = threadIdx.x; i < DIMM; i += 256)
    o[(size_t)row * DIMM + i] = xr[i] * scale * w[i];
}

extern "C" void kernel_launch(void* const* d_in, const int* in_sizes, int n_in,
                              void* d_out, int out_size, void* d_ws, size_t ws_size,
                              hipStream_t stream) {
  (void)in_sizes; (void)n_in; (void)out_size; (void)ws_size;
  const float* x_in    = (const float*)d_in[0];
  const float* Wi_all  = (const float*)d_in[1];
  const float* cw_all  = (const float*)d_in[2];
  const float* cb_all  = (const float*)d_in[3];
  const float* Wx_all  = (const float*)d_in[4];
  const float* Wdt_all = (const float*)d_in[5];
  const float* bdt_all = (const float*)d_in[6];
  const float* Alog_all= (const float*)d_in[7];
  const float* D_all   = (const float*)d_in[8];
  const float* Wo_all  = (const float*)d_in[9];
  const float* rw_all  = (const float*)d_in[10];
  float* out = (float*)d_out;

  // Workspace layout (floats); ~152.6 MB total (same as R1).
  float* ws    = (float*)d_ws;
  float* xz    = ws;                          // MM*2*DI  = 16777216
  float* xc    = xz   + (size_t)MM * 2 * DI;  // MM*DI    =  8388608
  float* xdbl  = xc   + (size_t)MM * DI;      // MM*96    =   393216
  float* delta = xdbl + (size_t)MM * 96;      // MM*DI    =  8388608
  float* xbuf  = delta+ (size_t)MM * DI;      // MM*DIMM  =  4194304
  float* outtmp = xc;  // xc dead after scan; conv of next layer rewrites it

  const int EW_GRID = (MM * DI) / 256;        // 32768 blocks

  for (int i = 0; i < DEPTH; ++i) {
    const float* Wi   = Wi_all  + (size_t)i * (2*DI) * DIMM;
    const float* cw   = cw_all  + (size_t)i * DI * DCONVK;
    const float* cb   = cb_all  + (size_t)i * DI;
    const float* Wx   = Wx_all  + (size_t)i * 96 * DI;
    const float* Wdt  = Wdt_all + (size_t)i * DI * DTRANK;
    const float* bdt  = bdt_all + (size_t)i * DI;
    const float* Alog = Alog_all+ (size_t)i * DI * NST;
    const float* Dp   = D_all   + (size_t)i * DI;
    const float* Wo   = Wo_all  + (size_t)i * DIMM * DI;
    const float* rw   = rw_all  + (size_t)i * DIMM;
    const float* xin  = (i == 0) ? x_in : xbuf;
    float* xout = (i == DEPTH - 1) ? out : xbuf;

    // 1) in_proj: xz[MM, 2*DI] = x[MM, DIMM] * Wi[2*DI, DIMM]^T
    gemm_nt<<<dim3((2*DI)/TBN, MM/TBM), 256, 0, stream>>>(xin, DIMM, Wi, xz, MM, 2*DI, DIMM);
    // 2) depthwise causal conv + silu -> xc[MM, DI]
    conv_silu_k<<<EW_GRID, 256, 0, stream>>>(xz, cw, cb, xc);
    // 3) x_proj: xdbl[MM, 96] = xc * Wx^T
    gemm_nt<<<dim3(1, MM/TBM), 256, 0, stream>>>(xc, DI, Wx, xdbl, MM, 96, DI);
    // 4) dt_proj: delta[MM, DI] = xdbl[:, :64] (lda=96) * Wdt^T
    gemm_nt<<<dim3(DI/TBN, MM/TBM), 256, 0, stream>>>(xdbl, 96, Wdt, delta, MM, DI, DTRANK);
    // 5) delta = softplus(delta + bdt)
    bias_softplus_k<<<EW_GRID, 256, 0, stream>>>(delta, bdt);
    // 6) selective scan + D-skip + silu(z) gate (fused); y overwrites delta
    scan_k<<<(BB*DI)/16, 256, 0, stream>>>(delta, xc, xdbl, Alog, xz, Dp);
    // 7) out_proj: outtmp[MM, DIMM] = y * Wo^T
    gemm_nt<<<dim3(DIMM/TBN, MM/TBM), 256, 0, stream>>>(delta, DI, Wo, outtmp, MM, DIMM, DI);
    // 8) rmsnorm -> next x (or d_out)
    rmsnorm_k<<<MM, 256, 0, stream>>>(outtmp, rw, xout);
  }
}

// Round 3
// 10662.669 us; speedup vs baseline: 1.6254x; 1.2602x over previous
//
#include <hip/hip_runtime.h>
#include <cstddef>

// Problem constants (fixed by the reference)
#define DEPTH  8
#define DIMM   1024
#define DI     2048      // d_inner
#define NST    16        // d_state
#define DCONVK 4
#define DTRANK 64
#define BB     2
#define LL     2048
#define MM     (BB*LL)   // 4096 rows
#define BD     (BB*DI)   // 4096 channels
#define CHK    16        // scan chunks
#define LC     (LL/CHK)  // 128 timesteps per chunk
#define LOG2E  1.44269504088896f

// ---------------- GEMM: C[M,N] = A[M,K] (lda) * W[N,K]^T ----------------
#define TBM 128
#define TBN 128
#define TBK 16

__global__ __launch_bounds__(256) void gemm_nt(const float* __restrict__ A, int lda,
                                               const float* __restrict__ W,
                                               float* __restrict__ C,
                                               int M, int N, int K) {
  __shared__ float As[TBK][TBM];
  __shared__ float Ws[TBK][TBN];
  const int t  = threadIdx.x;
  const int tx = t & 15;
  const int ty = (t >> 4) & 15;
  const int m0 = blockIdx.y * TBM;
  const int n0 = blockIdx.x * TBN;

  float acc[8][8];
#pragma unroll
  for (int i = 0; i < 8; ++i)
#pragma unroll
    for (int j = 0; j < 8; ++j) acc[i][j] = 0.f;

  for (int k0 = 0; k0 < K; k0 += TBK) {
#pragma unroll
    for (int j = 0; j < 2; ++j) {
      int e  = t + j * 256;        // 512 float4 slots per tile
      int r  = e >> 2;             // 0..127
      int cq = (e & 3) << 2;       // 0,4,8,12
      const float* ap = A + (size_t)(m0 + r) * lda + (k0 + cq);
      float4 v = *(const float4*)ap;
      As[cq+0][r] = v.x; As[cq+1][r] = v.y; As[cq+2][r] = v.z; As[cq+3][r] = v.w;
      int n = n0 + r;
      float4 w;
      if (n < N) w = *(const float4*)(W + (size_t)n * K + (k0 + cq));
      else { w.x = 0.f; w.y = 0.f; w.z = 0.f; w.w = 0.f; }
      Ws[cq+0][r] = w.x; Ws[cq+1][r] = w.y; Ws[cq+2][r] = w.z; Ws[cq+3][r] = w.w;
    }
    __syncthreads();
#pragma unroll
    for (int kk = 0; kk < TBK; ++kk) {
      float a[8], b[8];
#pragma unroll
      for (int i = 0; i < 4; ++i) { a[i] = As[kk][ty*4 + i]; a[i+4] = As[kk][64 + ty*4 + i]; }
#pragma unroll
      for (int j = 0; j < 4; ++j) { b[j] = Ws[kk][tx*4 + j]; b[j+4] = Ws[kk][64 + tx*4 + j]; }
#pragma unroll
      for (int i = 0; i < 8; ++i)
#pragma unroll
        for (int j = 0; j < 8; ++j) acc[i][j] += a[i] * b[j];
    }
    __syncthreads();
  }

#pragma unroll
  for (int i = 0; i < 8; ++i) {
    int m = m0 + ((i < 4) ? (ty*4 + i) : (64 + ty*4 + (i - 4)));
#pragma unroll
    for (int jh = 0; jh < 2; ++jh) {
      int n = n0 + jh*64 + tx*4;
      if (n < N) {
        float4 v;
        v.x = acc[i][jh*4+0]; v.y = acc[i][jh*4+1];
        v.z = acc[i][jh*4+2]; v.w = acc[i][jh*4+3];
        *(float4*)(C + (size_t)m * N + n) = v;
      }
    }
  }
}

__device__ __forceinline__ float fast_silu(float x) {
  // x * sigmoid(x), sigmoid via exp2 + hw rcp (~1ulp; precision margin is 13x)
  return x * __builtin_amdgcn_rcpf(1.f + exp2f(-LOG2E * x));
}

// ---------------- depthwise causal conv1d + SiLU ----------------
__global__ __launch_bounds__(256) void conv_silu_k(const float* __restrict__ xz,
                                                   const float* __restrict__ cw,
                                                   const float* __restrict__ cb,
                                                   float* __restrict__ xc) {
  int idx = blockIdx.x * 256 + threadIdx.x;   // over MM*DI
  int c  = idx & (DI - 1);
  int bl = idx >> 11;
  int l  = bl & (LL - 1);
  float acc = cb[c];
#pragma unroll
  for (int k = 0; k < DCONVK; ++k) {
    int ls = l - (DCONVK - 1) + k;
    if (ls >= 0)
      acc += xz[(size_t)(bl - (DCONVK - 1) + k) * (2*DI) + c] * cw[c*DCONVK + k];
  }
  xc[idx] = fast_silu(acc);
}

// ---------------- bias + softplus (in-place on delta) ----------------
__global__ __launch_bounds__(256) void bias_softplus_k(float* __restrict__ delta,
                                                       const float* __restrict__ bdt) {
  int idx = blockIdx.x * 256 + threadIdx.x;
  int c = idx & (DI - 1);
  float x = delta[idx] + bdt[c];
  delta[idx] = fmaxf(x, 0.f) + log1pf(expf(-fabsf(x)));  // stable softplus
}

// ======================= chunked selective scan =======================
// h_t = exp(dt*A)*h + dt*x*B   is a 1st-order linear recurrence (associative).
// Pass 1: per (chunk,ch,n): zero-init chunk scan -> H_c; also S_c = sum(dt).
//         Chunk decay product = exp2(Av2 * S_c) exactly (single exp).
// Pass 2: per (ch,n): sequential combine over 16 chunks -> h_start[c].
// Pass 3: per (chunk,ch,n): re-scan from h_start, emit gated y (in-place on delta).
// 16x the wave count of the monolithic scan -> TLP hides shuffle/exp latency.

__global__ __launch_bounds__(256) void scan_pass1(const float* __restrict__ delta,
                                                  const float* __restrict__ xc,
                                                  const float* __restrict__ xdbl,
                                                  const float* __restrict__ A_log,
                                                  float* __restrict__ Hc,
                                                  float* __restrict__ Sdt) {
  const int g   = blockIdx.x * 256 + threadIdx.x;  // [c][ch][n]
  const int n   = g & (NST - 1);
  const int rest= g >> 4;
  const int ch  = rest & (BD - 1);
  const int c   = rest >> 12;          // BD = 4096 = 2^12
  const int b   = ch >> 11;
  const int d   = ch & (DI - 1);
  const float Av2 = -expf(A_log[d * NST + n]) * LOG2E;

  size_t row0 = (size_t)b * LL + (size_t)c * LC;
  const float* pd = delta + row0 * DI + d;
  const float* px = xc    + row0 * DI + d;
  const float* pB = xdbl  + row0 * 96 + DTRANK + n;

  float h = 0.f, S = 0.f;
  for (int l = 0; l < LC; l += 4) {
    float dt[4], xv[4], Bv[4];
#pragma unroll
    for (int u = 0; u < 4; ++u) {
      dt[u] = pd[(size_t)u * DI];
      xv[u] = px[(size_t)u * DI];
      Bv[u] = pB[(size_t)u * 96];
    }
#pragma unroll
    for (int u = 0; u < 4; ++u) {
      h = fmaf(exp2f(dt[u] * Av2), h, dt[u] * xv[u] * Bv[u]);
      S += dt[u];
    }
    pd += 4 * DI; px += 4 * DI; pB += 4 * 96;
  }
  size_t idx = (size_t)c * BD + ch;
  Hc[idx * NST + n] = h;
  if (n == 0) Sdt[idx] = S;
}

__global__ __launch_bounds__(256) void scan_pass2(const float* __restrict__ Hc,
                                                  const float* __restrict__ Sdt,
                                                  const float* __restrict__ A_log,
                                                  float* __restrict__ hst) {
  const int g  = blockIdx.x * 256 + threadIdx.x;   // ch*16+n, 65536 total
  const int n  = g & (NST - 1);
  const int ch = g >> 4;
  const int d  = ch & (DI - 1);
  const float Av2 = -expf(A_log[d * NST + n]) * LOG2E;
  float h = 0.f;
#pragma unroll
  for (int c = 0; c < CHK; ++c) {
    size_t idx = (size_t)c * BD + ch;
    hst[idx * NST + n] = h;
    h = fmaf(exp2f(Av2 * Sdt[idx]), h, Hc[idx * NST + n]);
  }
}

#define SU 8
__global__ __launch_bounds__(256) void scan_pass3(float* dy,  // in: delta, out: y (in-place)
                                                  const float* __restrict__ xc,
                                                  const float* __restrict__ xdbl,
                                                  const float* __restrict__ A_log,
                                                  const float* __restrict__ xz,
                                                  const float* __restrict__ Dp,
                                                  const float* __restrict__ hst) {
  const int g   = blockIdx.x * 256 + threadIdx.x;  // [c][ch][n]
  const int n   = g & (NST - 1);
  const int rest= g >> 4;
  const int ch  = rest & (BD - 1);
  const int c   = rest >> 12;
  const int b   = ch >> 11;
  const int d   = ch & (DI - 1);
  const float Av2 = -expf(A_log[d * NST + n]) * LOG2E;
  const float Dv  = Dp[d];
  float h = hst[((size_t)c * BD + ch) * NST + n];
  const size_t rowbase = (size_t)b * LL + (size_t)c * LC;

  float aA[SU], aX[SU], aB[SU], aC[SU], aZ[SU];
  float bA[SU], bX[SU], bB[SU], bC[SU], bZ[SU];

#define LOADG(l0, A_, X_, B_, C_, Z_)                                 \
  {                                                                   \
    _Pragma("unroll")                                                 \
    for (int u = 0; u < SU; ++u) {                                    \
      size_t bl = rowbase + (l0) + u;                                 \
      A_[u] = dy  [bl * DI + d];                                      \
      X_[u] = xc  [bl * DI + d];                                      \
      B_[u] = xdbl[bl * 96 + DTRANK + n];                             \
      C_[u] = xdbl[bl * 96 + DTRANK + NST + n];                       \
      Z_[u] = xz  [bl * (2*DI) + DI + d];                             \
    }                                                                 \
  }

#define COMPG(l0, A_, X_, B_, C_, Z_)                                 \
  {                                                                   \
    _Pragma("unroll")                                                 \
    for (int u = 0; u < SU; ++u) {                                    \
      float dt = A_[u];                                               \
      h = fmaf(exp2f(dt * Av2), h, dt * X_[u] * B_[u]);               \
      float s = h * C_[u];                                            \
      s += __shfl_xor(s, 1, 16);                                      \
      s += __shfl_xor(s, 2, 16);                                      \
      s += __shfl_xor(s, 4, 16);                                      \
      s += __shfl_xor(s, 8, 16);                                      \
      float yv = (s + X_[u] * Dv) * fast_silu(Z_[u]);                 \
      if (n == 0) dy[(rowbase + (l0) + u) * DI + d] = yv;             \
    }                                                                 \
  }

  LOADG(0, aA, aX, aB, aC, aZ);
  for (int l0 = 0; l0 < LC; l0 += 2 * SU) {
    LOADG(l0 + SU, bA, bX, bB, bC, bZ);
    COMPG(l0, aA, aX, aB, aC, aZ);
    if (l0 + 2 * SU < LC)
      LOADG(l0 + 2 * SU, aA, aX, aB, aC, aZ);
    COMPG(l0 + SU, bA, bX, bB, bC, bZ);
  }
#undef LOADG
#undef COMPG
}

// ---------------- RMSNorm over rows of DIMM ----------------
__global__ __launch_bounds__(256) void rmsnorm_k(const float* __restrict__ x,
                                                 const float* __restrict__ w,
                                                 float* __restrict__ o) {
  int row = blockIdx.x;
  const float* xr = x + (size_t)row * DIMM;
  float s = 0.f;
  for (int i = threadIdx.x; i < DIMM; i += 256) { float v = xr[i]; s += v * v; }
#pragma unroll
  for (int off = 32; off > 0; off >>= 1) s += __shfl_xor(s, off, 64);
  __shared__ float red[4];
  if ((threadIdx.x & 63) == 0) red[threadIdx.x >> 6] = s;
  __syncthreads();
  float tot = red[0] + red[1] + red[2] + red[3];
  float scale = rsqrtf(tot * (1.0f / DIMM) + 1e-5f);
  for (int i = threadIdx.x; i < DIMM; i += 256)
    o[(size_t)row * DIMM + i] = xr[i] * scale * w[i];
}

extern "C" void kernel_launch(void* const* d_in, const int* in_sizes, int n_in,
                              void* d_out, int out_size, void* d_ws, size_t ws_size,
                              hipStream_t stream) {
  (void)in_sizes; (void)n_in; (void)out_size; (void)ws_size;
  const float* x_in    = (const float*)d_in[0];
  const float* Wi_all  = (const float*)d_in[1];
  const float* cw_all  = (const float*)d_in[2];
  const float* cb_all  = (const float*)d_in[3];
  const float* Wx_all  = (const float*)d_in[4];
  const float* Wdt_all = (const float*)d_in[5];
  const float* bdt_all = (const float*)d_in[6];
  const float* Alog_all= (const float*)d_in[7];
  const float* D_all   = (const float*)d_in[8];
  const float* Wo_all  = (const float*)d_in[9];
  const float* rw_all  = (const float*)d_in[10];
  float* out = (float*)d_out;

  // Workspace layout (floats); ~152.6 MB total (unchanged from R2).
  float* ws    = (float*)d_ws;
  float* xz    = ws;                          // MM*2*DI  = 16777216
  float* xc    = xz   + (size_t)MM * 2 * DI;  // MM*DI    =  8388608
  float* xdbl  = xc   + (size_t)MM * DI;      // MM*96    =   393216
  float* delta = xdbl + (size_t)MM * 96;      // MM*DI    =  8388608
  float* xbuf  = delta+ (size_t)MM * DI;      // MM*DIMM  =  4194304
  float* outtmp = xc;  // xc dead after scan; conv of next layer rewrites it

  // Scan scratch aliases xbuf: xbuf is only read by in_proj (step 1) and only
  // rewritten by rmsnorm (step 8); scan (steps 6a-c) sits strictly between on
  // the same stream, so the region is dead during the scan. 8.25MB < 16MB.
  float* Hc  = xbuf;                              // CHK*BD*NST = 1048576
  float* hst = Hc  + (size_t)CHK * BD * NST;      // CHK*BD*NST = 1048576
  float* Sdt = hst + (size_t)CHK * BD * NST;      // CHK*BD     =   65536

  const int EW_GRID = (MM * DI) / 256;        // 32768 blocks

  for (int i = 0; i < DEPTH; ++i) {
    const float* Wi   = Wi_all  + (size_t)i * (2*DI) * DIMM;
    const float* cw   = cw_all  + (size_t)i * DI * DCONVK;
    const float* cb   = cb_all  + (size_t)i * DI;
    const float* Wx   = Wx_all  + (size_t)i * 96 * DI;
    const float* Wdt  = Wdt_all + (size_t)i * DI * DTRANK;
    const float* bdt  = bdt_all + (size_t)i * DI;
    const float* Alog = Alog_all+ (size_t)i * DI * NST;
    const float* Dp   = D_all   + (size_t)i * DI;
    const float* Wo   = Wo_all  + (size_t)i * DIMM * DI;
    const float* rw   = rw_all  + (size_t)i * DIMM;
    const float* xin  = (i == 0) ? x_in : xbuf;
    float* xout = (i == DEPTH - 1) ? out : xbuf;

    // 1) in_proj: xz[MM, 2*DI] = x[MM, DIMM] * Wi[2*DI, DIMM]^T
    gemm_nt<<<dim3((2*DI)/TBN, MM/TBM), 256, 0, stream>>>(xin, DIMM, Wi, xz, MM, 2*DI, DIMM);
    // 2) depthwise causal conv + silu -> xc[MM, DI]
    conv_silu_k<<<EW_GRID, 256, 0, stream>>>(xz, cw, cb, xc);
    // 3) x_proj: xdbl[MM, 96] = xc * Wx^T
    gemm_nt<<<dim3(1, MM/TBM), 256, 0, stream>>>(xc, DI, Wx, xdbl, MM, 96, DI);
    // 4) dt_proj: delta[MM, DI] = xdbl[:, :64] (lda=96) * Wdt^T
    gemm_nt<<<dim3(DI/TBN, MM/TBM), 256, 0, stream>>>(xdbl, 96, Wdt, delta, MM, DI, DTRANK);
    // 5) delta = softplus(delta + bdt)
    bias_softplus_k<<<EW_GRID, 256, 0, stream>>>(delta, bdt);
    // 6) chunked selective scan + D-skip + silu(z) gate; y overwrites delta
    scan_pass1<<<(CHK*BD*NST)/256, 256, 0, stream>>>(delta, xc, xdbl, Alog, Hc, Sdt);
    scan_pass2<<<(BD*NST)/256, 256, 0, stream>>>(Hc, Sdt, Alog, hst);
    scan_pass3<<<(CHK*BD*NST)/256, 256, 0, stream>>>(delta, xc, xdbl, Alog, xz, Dp, hst);
    // 7) out_proj: outtmp[MM, DIMM] = y * Wo^T
    gemm_nt<<<dim3(DIMM/TBN, MM/TBM), 256, 0, stream>>>(delta, DI, Wo, outtmp, MM, DIMM, DI);
    // 8) rmsnorm -> next x (or d_out)
    rmsnorm_k<<<MM, 256, 0, stream>>>(outtmp, rw, xout);
  }
}

// Round 4
// 5497.181 us; speedup vs baseline: 3.1527x; 1.9397x over previous
//
#include <hip/hip_runtime.h>
#include <cstddef>

// Problem constants (fixed by the reference)
#define DEPTH  8
#define DIMM   1024
#define DI     2048      // d_inner
#define NST    16        // d_state
#define DCONVK 4
#define DTRANK 64
#define BB     2
#define LL     2048
#define MM     (BB*LL)   // 4096 rows
#define BD     (BB*DI)   // 4096 channels
#define CHK    16        // scan chunks
#define LC     (LL/CHK)  // 128 timesteps per chunk
#define LOG2E  1.44269504088896f

typedef __attribute__((ext_vector_type(8))) short bf16x8;
typedef __attribute__((ext_vector_type(4))) float f32x4;

// ================= fp32 -> 3x bf16 plane split =================
__device__ __forceinline__ unsigned short f2bf(float f) {
  unsigned int u = __float_as_uint(f);
  unsigned int r = (u + 0x7fffu + ((u >> 16) & 1u)) >> 16;   // RNE
  return (unsigned short)r;
}
__device__ __forceinline__ float bf2f(unsigned short h) {
  return __uint_as_float(((unsigned int)h) << 16);
}

// x[n] fp32 -> planes p[0..n), p[n..2n), p[2n..3n) bf16 (hi, mid, lo)
__global__ __launch_bounds__(256) void cvt3_k(const float* __restrict__ x,
                                              unsigned short* __restrict__ p,
                                              size_t n) {
  size_t i = ((size_t)blockIdx.x * 256 + threadIdx.x) * 4;
  float4 v = *(const float4*)(x + i);
  float vv[4] = {v.x, v.y, v.z, v.w};
  unsigned short u1[4], u2[4], u3[4];
#pragma unroll
  for (int k = 0; k < 4; ++k) {
    float f = vv[k];
    unsigned short h1 = f2bf(f);  float r1 = f  - bf2f(h1);
    unsigned short h2 = f2bf(r1); float r2 = r1 - bf2f(h2);
    unsigned short h3 = f2bf(r2);
    u1[k] = h1; u2[k] = h2; u3[k] = h3;
  }
  *(ushort4*)(p + i)         = make_ushort4(u1[0], u1[1], u1[2], u1[3]);
  *(ushort4*)(p + n + i)     = make_ushort4(u2[0], u2[1], u2[2], u2[3]);
  *(ushort4*)(p + 2*n + i)   = make_ushort4(u3[0], u3[1], u3[2], u3[3]);
}

// ======== multi-plane bf16 MFMA GEMM: C[M,N] = A[M,K] * B[N,K]^T ========
// A,B given as bf16 planes (stride M*K / N*K). NPROD=3: (0,0),(0,1),(1,0)
// [stages 2 planes]; NPROD=6: +(0,2),(1,1),(2,0) [stages 3 planes].
// 128x128 block tile, BK=32, 4 waves, each wave 64x64 via 4x4 of 16x16x32
// MFMA. Staging via global_load_lds width=16 (wave-uniform LDS base+lane*16).
template <int NPROD>
__global__ __launch_bounds__(256) void gemm_mp(const unsigned short* __restrict__ Ap,
                                               const unsigned short* __restrict__ Bp,
                                               float* __restrict__ C,
                                               int M, int N, int K) {
  constexpr int NP    = (NPROD == 6) ? 3 : 2;   // planes staged per matrix
  constexpr int NCH   = NP * 2 * 512;           // 16B chunks per K-tile
  constexpr int ITERS = NCH / 256;
  __shared__ unsigned short S[NP * 2 * 128 * 32];

  const int t  = threadIdx.x;
  const int w  = t >> 6;
  const int l  = t & 63;
  const int lm = l & 15;
  const int q8 = (l >> 4) << 3;
  const int m0 = blockIdx.y * 128;
  const int n0 = blockIdx.x * 128;
  const int wm = (w & 1) << 6;
  const int wn = (w >> 1) << 6;

  // per-thread staging sources; LDS dest is wave-uniform (lane scatter is HW)
  const unsigned short* src[ITERS];
  unsigned short* dst[ITERS];
#pragma unroll
  for (int it = 0; it < ITERS; ++it) {
    int c  = it * 256 + t;
    int p  = c >> 9;                 // plane-tile index
    int wi = c & 511;
    int r  = wi >> 2;                // row within tile
    int kq = (wi & 3) << 3;          // k offset (8 bf16 = 16B)
    const unsigned short* base = (p < NP)
        ? (Ap + (size_t)p * M * K + (size_t)(m0 + r) * K)
        : (Bp + (size_t)(p - NP) * N * K + (size_t)(n0 + r) * K);
    src[it] = base + kq;
    dst[it] = &S[(size_t)(it * 256 + (w << 6)) * 8];
  }

  f32x4 acc[4][4];
#pragma unroll
  for (int i = 0; i < 4; ++i)
#pragma unroll
    for (int j = 0; j < 4; ++j) acc[i][j] = (f32x4){0.f, 0.f, 0.f, 0.f};

  constexpr int PI[6] = {0, 0, 1, 0, 1, 2};
  constexpr int PJ[6] = {0, 1, 0, 2, 1, 0};

  for (int k0 = 0; k0 < K; k0 += 32) {
#pragma unroll
    for (int it = 0; it < ITERS; ++it) {
      __builtin_amdgcn_global_load_lds(
          (const __attribute__((address_space(1))) unsigned int*)src[it],
          (__attribute__((address_space(3))) unsigned int*)dst[it], 16, 0, 0);
      src[it] += 32;
    }
    __syncthreads();   // drains vmcnt before any wave reads LDS
#pragma unroll
    for (int pp = 0; pp < NPROD; ++pp) {
      const int pi = PI[pp], pj = PJ[pp];
      bf16x8 av[4], bv[4];
#pragma unroll
      for (int i = 0; i < 4; ++i)
        av[i] = *(const bf16x8*)&S[pi * 4096 + (wm + i * 16 + lm) * 32 + q8];
#pragma unroll
      for (int j = 0; j < 4; ++j)
        bv[j] = *(const bf16x8*)&S[(NP + pj) * 4096 + (wn + j * 16 + lm) * 32 + q8];
#pragma unroll
      for (int i = 0; i < 4; ++i)
#pragma unroll
        for (int j = 0; j < 4; ++j)
          acc[i][j] = __builtin_amdgcn_mfma_f32_16x16x32_bf16(av[i], bv[j], acc[i][j], 0, 0, 0);
    }
    __syncthreads();
  }

  // C/D layout: col = lane&15, row = (lane>>4)*4 + reg  (m89/m91-verified)
  const int row0 = (l >> 4) << 2;
#pragma unroll
  for (int i = 0; i < 4; ++i)
#pragma unroll
    for (int j = 0; j < 4; ++j)
#pragma unroll
      for (int r = 0; r < 4; ++r) {
        int m = m0 + wm + i * 16 + row0 + r;
        int n = n0 + wn + j * 16 + lm;
        C[(size_t)m * N + n] = acc[i][j][r];
      }
}

// ---------------- fp32 GEMM (kept for dt_proj, K=64) ----------------
#define TBM 128
#define TBN 128
#define TBK 16
__global__ __launch_bounds__(256) void gemm_nt(const float* __restrict__ A, int lda,
                                               const float* __restrict__ W,
                                               float* __restrict__ C,
                                               int M, int N, int K) {
  __shared__ float As[TBK][TBM];
  __shared__ float Ws[TBK][TBN];
  const int t  = threadIdx.x;
  const int tx = t & 15;
  const int ty = (t >> 4) & 15;
  const int m0 = blockIdx.y * TBM;
  const int n0 = blockIdx.x * TBN;

  float acc[8][8];
#pragma unroll
  for (int i = 0; i < 8; ++i)
#pragma unroll
    for (int j = 0; j < 8; ++j) acc[i][j] = 0.f;

  for (int k0 = 0; k0 < K; k0 += TBK) {
#pragma unroll
    for (int j = 0; j < 2; ++j) {
      int e  = t + j * 256;
      int r  = e >> 2;
      int cq = (e & 3) << 2;
      const float* ap = A + (size_t)(m0 + r) * lda + (k0 + cq);
      float4 v = *(const float4*)ap;
      As[cq+0][r] = v.x; As[cq+1][r] = v.y; As[cq+2][r] = v.z; As[cq+3][r] = v.w;
      int n = n0 + r;
      float4 w2;
      if (n < N) w2 = *(const float4*)(W + (size_t)n * K + (k0 + cq));
      else { w2.x = 0.f; w2.y = 0.f; w2.z = 0.f; w2.w = 0.f; }
      Ws[cq+0][r] = w2.x; Ws[cq+1][r] = w2.y; Ws[cq+2][r] = w2.z; Ws[cq+3][r] = w2.w;
    }
    __syncthreads();
#pragma unroll
    for (int kk = 0; kk < TBK; ++kk) {
      float a[8], b[8];
#pragma unroll
      for (int i = 0; i < 4; ++i) { a[i] = As[kk][ty*4 + i]; a[i+4] = As[kk][64 + ty*4 + i]; }
#pragma unroll
      for (int j = 0; j < 4; ++j) { b[j] = Ws[kk][tx*4 + j]; b[j+4] = Ws[kk][64 + tx*4 + j]; }
#pragma unroll
      for (int i = 0; i < 8; ++i)
#pragma unroll
        for (int j = 0; j < 8; ++j) acc[i][j] += a[i] * b[j];
    }
    __syncthreads();
  }
#pragma unroll
  for (int i = 0; i < 8; ++i) {
    int m = m0 + ((i < 4) ? (ty*4 + i) : (64 + ty*4 + (i - 4)));
#pragma unroll
    for (int jh = 0; jh < 2; ++jh) {
      int n = n0 + jh*64 + tx*4;
      if (n < N) {
        float4 v;
        v.x = acc[i][jh*4+0]; v.y = acc[i][jh*4+1];
        v.z = acc[i][jh*4+2]; v.w = acc[i][jh*4+3];
        *(float4*)(C + (size_t)m * N + n) = v;
      }
    }
  }
}

// ---------------- x_proj split-K: C[4096,96] = xc * Wx^T ----------------
#define XPN 96
__global__ __launch_bounds__(256) void xproj_part_k(const float* __restrict__ A,
                                                    const float* __restrict__ W,
                                                    float* __restrict__ Cp) {
  __shared__ float As[16][128];
  __shared__ float Ws[16][XPN];
  const int t  = threadIdx.x;
  const int tx = t & 15;        // 6 cols each
  const int ty = t >> 4;        // 8 rows each
  const int m0 = blockIdx.x * 128;
  const int kb = blockIdx.y * 256;
  float acc[8][6];
#pragma unroll
  for (int i = 0; i < 8; ++i)
#pragma unroll
    for (int j = 0; j < 6; ++j) acc[i][j] = 0.f;

  for (int k0 = kb; k0 < kb + 256; k0 += 16) {
#pragma unroll
    for (int e = t; e < 512; e += 256) {
      int r = e >> 2, cq = (e & 3) << 2;
      float4 v = *(const float4*)(A + (size_t)(m0 + r) * DI + k0 + cq);
      As[cq+0][r] = v.x; As[cq+1][r] = v.y; As[cq+2][r] = v.z; As[cq+3][r] = v.w;
    }
    for (int e = t; e < 384; e += 256) {
      int r = e >> 2, cq = (e & 3) << 2;
      float4 v = *(const float4*)(W + (size_t)r * DI + k0 + cq);
      Ws[cq+0][r] = v.x; Ws[cq+1][r] = v.y; Ws[cq+2][r] = v.z; Ws[cq+3][r] = v.w;
    }
    __syncthreads();
#pragma unroll
    for (int kk = 0; kk < 16; ++kk) {
      float a[8], b[6];
#pragma unroll
      for (int i = 0; i < 8; ++i) a[i] = As[kk][ty*8 + i];
#pragma unroll
      for (int j = 0; j < 6; ++j) b[j] = Ws[kk][tx*6 + j];
#pragma unroll
      for (int i = 0; i < 8; ++i)
#pragma unroll
        for (int j = 0; j < 6; ++j) acc[i][j] += a[i] * b[j];
    }
    __syncthreads();
  }
  float* cp = Cp + (size_t)blockIdx.y * MM * XPN;
#pragma unroll
  for (int i = 0; i < 8; ++i)
#pragma unroll
    for (int j = 0; j < 6; ++j)
      cp[(size_t)(m0 + ty*8 + i) * XPN + tx*6 + j] = acc[i][j];
}

__global__ __launch_bounds__(256) void xproj_red_k(const float* __restrict__ Cp,
                                                   float* __restrict__ o) {
  int i = blockIdx.x * 256 + threadIdx.x;     // grid covers 4096*96
  float s = 0.f;
#pragma unroll
  for (int ks = 0; ks < 8; ++ks) s += Cp[(size_t)ks * (MM * XPN) + i];
  o[i] = s;
}

__device__ __forceinline__ float fast_silu(float x) {
  return x * __builtin_amdgcn_rcpf(1.f + exp2f(-LOG2E * x));
}

// ---------------- depthwise causal conv1d + SiLU ----------------
__global__ __launch_bounds__(256) void conv_silu_k(const float* __restrict__ xz,
                                                   const float* __restrict__ cw,
                                                   const float* __restrict__ cb,
                                                   float* __restrict__ xc) {
  int idx = blockIdx.x * 256 + threadIdx.x;
  int c  = idx & (DI - 1);
  int bl = idx >> 11;
  int l  = bl & (LL - 1);
  float acc = cb[c];
#pragma unroll
  for (int k = 0; k < DCONVK; ++k) {
    int ls = l - (DCONVK - 1) + k;
    if (ls >= 0)
      acc += xz[(size_t)(bl - (DCONVK - 1) + k) * (2*DI) + c] * cw[c*DCONVK + k];
  }
  xc[idx] = fast_silu(acc);
}

__global__ __launch_bounds__(256) void bias_softplus_k(float* __restrict__ delta,
                                                       const float* __restrict__ bdt) {
  int idx = blockIdx.x * 256 + threadIdx.x;
  int c = idx & (DI - 1);
  float x = delta[idx] + bdt[c];
  delta[idx] = fmaxf(x, 0.f) + log1pf(expf(-fabsf(x)));
}

// ======================= chunked selective scan =======================
__global__ __launch_bounds__(256) void scan_pass1(const float* __restrict__ delta,
                                                  const float* __restrict__ xc,
                                                  const float* __restrict__ xdbl,
                                                  const float* __restrict__ A_log,
                                                  float* __restrict__ Hc,
                                                  float* __restrict__ Sdt) {
  const int g   = blockIdx.x * 256 + threadIdx.x;
  const int n   = g & (NST - 1);
  const int rest= g >> 4;
  const int ch  = rest & (BD - 1);
  const int c   = rest >> 12;
  const int b   = ch >> 11;
  const int d   = ch & (DI - 1);
  const float Av2 = -expf(A_log[d * NST + n]) * LOG2E;

  size_t row0 = (size_t)b * LL + (size_t)c * LC;
  const float* pd = delta + row0 * DI + d;
  const float* px = xc    + row0 * DI + d;
  const float* pB = xdbl  + row0 * 96 + DTRANK + n;

  float h = 0.f, S = 0.f;
  for (int l = 0; l < LC; l += 4) {
    float dt[4], xv[4], Bv[4];
#pragma unroll
    for (int u = 0; u < 4; ++u) {
      dt[u] = pd[(size_t)u * DI];
      xv[u] = px[(size_t)u * DI];
      Bv[u] = pB[(size_t)u * 96];
    }
#pragma unroll
    for (int u = 0; u < 4; ++u) {
      h = fmaf(exp2f(dt[u] * Av2), h, dt[u] * xv[u] * Bv[u]);
      S += dt[u];
    }
    pd += 4 * DI; px += 4 * DI; pB += 4 * 96;
  }
  size_t idx = (size_t)c * BD + ch;
  Hc[idx * NST + n] = h;
  if (n == 0) Sdt[idx] = S;
}

__global__ __launch_bounds__(256) void scan_pass2(const float* __restrict__ Hc,
                                                  const float* __restrict__ Sdt,
                                                  const float* __restrict__ A_log,
                                                  float* __restrict__ hst) {
  const int g  = blockIdx.x * 256 + threadIdx.x;
  const int n  = g & (NST - 1);
  const int ch = g >> 4;
  const int d  = ch & (DI - 1);
  const float Av2 = -expf(A_log[d * NST + n]) * LOG2E;
  float h = 0.f;
#pragma unroll
  for (int c = 0; c < CHK; ++c) {
    size_t idx = (size_t)c * BD + ch;
    hst[idx * NST + n] = h;
    h = fmaf(exp2f(Av2 * Sdt[idx]), h, Hc[idx * NST + n]);
  }
}

#define SU 8
__global__ __launch_bounds__(256) void scan_pass3(float* dy,
                                                  const float* __restrict__ xc,
                                                  const float* __restrict__ xdbl,
                                                  const float* __restrict__ A_log,
                                                  const float* __restrict__ xz,
                                                  const float* __restrict__ Dp,
                                                  const float* __restrict__ hst) {
  const int g   = blockIdx.x * 256 + threadIdx.x;
  const int n   = g & (NST - 1);
  const int rest= g >> 4;
  const int ch  = rest & (BD - 1);
  const int c   = rest >> 12;
  const int b   = ch >> 11;
  const int d   = ch & (DI - 1);
  const float Av2 = -expf(A_log[d * NST + n]) * LOG2E;
  const float Dv  = Dp[d];
  float h = hst[((size_t)c * BD + ch) * NST + n];
  const size_t rowbase = (size_t)b * LL + (size_t)c * LC;

  float aA[SU], aX[SU], aB[SU], aC[SU], aZ[SU];
  float bA[SU], bX[SU], bB[SU], bC[SU], bZ[SU];

#define LOADG(l0, A_, X_, B_, C_, Z_)                                 \
  {                                                                   \
    _Pragma("unroll")                                                 \
    for (int u = 0; u < SU; ++u) {                                    \
      size_t bl = rowbase + (l0) + u;                                 \
      A_[u] = dy  [bl * DI + d];                                      \
      X_[u] = xc  [bl * DI + d];                                      \
      B_[u] = xdbl[bl * 96 + DTRANK + n];                             \
      C_[u] = xdbl[bl * 96 + DTRANK + NST + n];                       \
      Z_[u] = xz  [bl * (2*DI) + DI + d];                             \
    }                                                                 \
  }

#define COMPG(l0, A_, X_, B_, C_, Z_)                                 \
  {                                                                   \
    _Pragma("unroll")                                                 \
    for (int u = 0; u < SU; ++u) {                                    \
      float dt = A_[u];                                               \
      h = fmaf(exp2f(dt * Av2), h, dt * X_[u] * B_[u]);               \
      float s = h * C_[u];                                            \
      s += __shfl_xor(s, 1, 16);                                      \
      s += __shfl_xor(s, 2, 16);                                      \
      s += __shfl_xor(s, 4, 16);                                      \
      s += __shfl_xor(s, 8, 16);                                      \
      float yv = (s + X_[u] * Dv) * fast_silu(Z_[u]);                 \
      if (n == 0) dy[(rowbase + (l0) + u) * DI + d] = yv;             \
    }                                                                 \
  }

  LOADG(0, aA, aX, aB, aC, aZ);
  for (int l0 = 0; l0 < LC; l0 += 2 * SU) {
    LOADG(l0 + SU, bA, bX, bB, bC, bZ);
    COMPG(l0, aA, aX, aB, aC, aZ);
    if (l0 + 2 * SU < LC)
      LOADG(l0 + 2 * SU, aA, aX, aB, aC, aZ);
    COMPG(l0 + SU, bA, bX, bB, bC, bZ);
  }
#undef LOADG
#undef COMPG
}

// ---------------- RMSNorm ----------------
__global__ __launch_bounds__(256) void rmsnorm_k(const float* __restrict__ x,
                                                 const float* __restrict__ w,
                                                 float* __restrict__ o) {
  int row = blockIdx.x;
  const float* xr = x + (size_t)row * DIMM;
  float s = 0.f;
  for (int i = threadIdx.x; i < DIMM; i += 256) { float v = xr[i]; s += v * v; }
#pragma unroll
  for (int off = 32; off > 0; off >>= 1) s += __shfl_xor(s, off, 64);
  __shared__ float red[4];
  if ((threadIdx.x & 63) == 0) red[threadIdx.x >> 6] = s;
  __syncthreads();
  float tot = red[0] + red[1] + red[2] + red[3];
  float scale = rsqrtf(tot * (1.0f / DIMM) + 1e-5f);
  for (int i = threadIdx.x; i < DIMM; i += 256)
    o[(size_t)row * DIMM + i] = xr[i] * scale * w[i];
}

extern "C" void kernel_launch(void* const* d_in, const int* in_sizes, int n_in,
                              void* d_out, int out_size, void* d_ws, size_t ws_size,
                              hipStream_t stream) {
  (void)in_sizes; (void)n_in; (void)out_size; (void)ws_size;
  const float* x_in    = (const float*)d_in[0];
  const float* Wi_all  = (const float*)d_in[1];
  const float* cw_all  = (const float*)d_in[2];
  const float* cb_all  = (const float*)d_in[3];
  const float* Wx_all  = (const float*)d_in[4];
  const float* Wdt_all = (const float*)d_in[5];
  const float* bdt_all = (const float*)d_in[6];
  const float* Alog_all= (const float*)d_in[7];
  const float* D_all   = (const float*)d_in[8];
  const float* Wo_all  = (const float*)d_in[9];
  const float* rw_all  = (const float*)d_in[10];
  float* out = (float*)d_out;

  // Workspace layout (floats); ~152.8 MB (same footprint as R1-R3).
  float* ws    = (float*)d_ws;
  float* xz    = ws;                          // MM*2*DI  = 16777216 fl (67MB)
  float* xc    = xz   + (size_t)MM * 2 * DI;  // MM*DI    =  8388608 fl (33.5MB)
  float* xdbl  = xc   + (size_t)MM * DI;      // MM*96    =   393216 fl
  float* delta = xdbl + (size_t)MM * 96;      // MM*DI    =  8388608 fl (33.5MB)
  float* xbuf  = delta+ (size_t)MM * DI;      // MM*DIMM  =  4194304 fl
  float* outtmp = xc;

  // Aliased scratch (all uses are strictly stream-ordered between the
  // producing/consuming kernels of the regions they borrow):
  //  - x planes (24MB)  -> delta region (dead until dt_proj)
  //  - Wi planes (24MB) -> xc region (dead until conv)
  //  - x_proj partials (12.6MB) -> delta region (dead until dt_proj)
  //  - y planes (50.3MB) + Wo planes (12.6MB) -> xz region (dead after scan)
  //  - scan Hc/hst/Sdt (8.4MB) -> xbuf region (x consumed by cvt3 at step 1)
  unsigned short* xpl  = (unsigned short*)delta;
  unsigned short* wipl = (unsigned short*)xc;
  float*          Cp   = delta;
  unsigned short* ypl  = (unsigned short*)xz;
  unsigned short* wopl = (unsigned short*)xz + (size_t)3 * MM * DI;
  float* Hc  = xbuf;
  float* hst = Hc  + (size_t)CHK * BD * NST;
  float* Sdt = hst + (size_t)CHK * BD * NST;

  const int EW_GRID = (MM * DI) / 256;

  for (int i = 0; i < DEPTH; ++i) {
    const float* Wi   = Wi_all  + (size_t)i * (2*DI) * DIMM;
    const float* cw   = cw_all  + (size_t)i * DI * DCONVK;
    const float* cb   = cb_all  + (size_t)i * DI;
    const float* Wx   = Wx_all  + (size_t)i * 96 * DI;
    const float* Wdt  = Wdt_all + (size_t)i * DI * DTRANK;
    const float* bdt  = bdt_all + (size_t)i * DI;
    const float* Alog = Alog_all+ (size_t)i * DI * NST;
    const float* Dp   = D_all   + (size_t)i * DI;
    const float* Wo   = Wo_all  + (size_t)i * DIMM * DI;
    const float* rw   = rw_all  + (size_t)i * DIMM;
    const float* xin  = (i == 0) ? x_in : xbuf;
    float* xout = (i == DEPTH - 1) ? out : xbuf;
    const bool hiP = (i < 4);   // 6-product fp32-grade emulation early layers

    // 1) split x and Wi into bf16 planes
    cvt3_k<<<(MM*DIMM)/1024, 256, 0, stream>>>(xin, xpl, (size_t)MM * DIMM);
    cvt3_k<<<((2*DI)*DIMM)/1024, 256, 0, stream>>>(Wi, wipl, (size_t)(2*DI) * DIMM);
    // 2) in_proj: xz = x * Wi^T  (MFMA multi-plane)
    if (hiP) gemm_mp<6><<<dim3((2*DI)/128, MM/128), 256, 0, stream>>>(xpl, wipl, xz, MM, 2*DI, DIMM);
    else     gemm_mp<3><<<dim3((2*DI)/128, MM/128), 256, 0, stream>>>(xpl, wipl, xz, MM, 2*DI, DIMM);
    // 3) depthwise causal conv + silu -> xc
    conv_silu_k<<<EW_GRID, 256, 0, stream>>>(xz, cw, cb, xc);
    // 4) x_proj (split-K fp32): xdbl = xc * Wx^T
    xproj_part_k<<<dim3(MM/128, 8), 256, 0, stream>>>(xc, Wx, Cp);
    xproj_red_k<<<(MM*XPN)/256, 256, 0, stream>>>(Cp, xdbl);
    // 5) dt_proj (fp32, K=64): delta = xdbl[:, :64] * Wdt^T
    gemm_nt<<<dim3(DI/TBN, MM/TBM), 256, 0, stream>>>(xdbl, 96, Wdt, delta, MM, DI, DTRANK);
    // 6) delta = softplus(delta + bdt)
    bias_softplus_k<<<EW_GRID, 256, 0, stream>>>(delta, bdt);
    // 7) chunked selective scan + D-skip + silu(z) gate; y overwrites delta
    scan_pass1<<<(CHK*BD*NST)/256, 256, 0, stream>>>(delta, xc, xdbl, Alog, Hc, Sdt);
    scan_pass2<<<(BD*NST)/256, 256, 0, stream>>>(Hc, Sdt, Alog, hst);
    scan_pass3<<<(CHK*BD*NST)/256, 256, 0, stream>>>(delta, xc, xdbl, Alog, xz, Dp, hst);
    // 8) split y and Wo into bf16 planes (xz dead now)
    cvt3_k<<<(MM*DI)/1024, 256, 0, stream>>>(delta, ypl, (size_t)MM * DI);
    cvt3_k<<<(DIMM*DI)/1024, 256, 0, stream>>>(Wo, wopl, (size_t)DIMM * DI);
    // 9) out_proj: outtmp = y * Wo^T (MFMA multi-plane)
    if (hiP) gemm_mp<6><<<dim3(DIMM/128, MM/128), 256, 0, stream>>>(ypl, wopl, outtmp, MM, DIMM, DI);
    else     gemm_mp<3><<<dim3(DIMM/128, MM/128), 256, 0, stream>>>(ypl, wopl, outtmp, MM, DIMM, DI);
    // 10) rmsnorm -> next x (or d_out)
    rmsnorm_k<<<MM, 256, 0, stream>>>(outtmp, rw, xout);
  }
}

// Round 5
// 4179.113 us; speedup vs baseline: 4.1471x; 1.3154x over previous
//
#include <hip/hip_runtime.h>
#include <cstddef>

// Problem constants (fixed by the reference)
#define DEPTH  8
#define DIMM   1024
#define DI     2048      // d_inner
#define NST    16        // d_state
#define DCONVK 4
#define DTRANK 64
#define BB     2
#define LL     2048
#define MM     (BB*LL)   // 4096 rows
#define BD     (BB*DI)   // 4096 channels
#define CHK    32        // scan chunks
#define LC     (LL/CHK)  // 64 timesteps per chunk
#define LOG2E  1.44269504088896f

typedef __attribute__((ext_vector_type(8))) short bf16x8;
typedef __attribute__((ext_vector_type(4))) float f32x4;

// ================= fp32 -> 3x bf16 plane split =================
__device__ __forceinline__ unsigned short f2bf(float f) {
  unsigned int u = __float_as_uint(f);
  unsigned int r = (u + 0x7fffu + ((u >> 16) & 1u)) >> 16;   // RNE
  return (unsigned short)r;
}
__device__ __forceinline__ float bf2f(unsigned short h) {
  return __uint_as_float(((unsigned int)h) << 16);
}

__global__ __launch_bounds__(256) void cvt3_k(const float* __restrict__ x,
                                              unsigned short* __restrict__ p,
                                              size_t n) {
  size_t i = ((size_t)blockIdx.x * 256 + threadIdx.x) * 4;
  float4 v = *(const float4*)(x + i);
  float vv[4] = {v.x, v.y, v.z, v.w};
  unsigned short u1[4], u2[4], u3[4];
#pragma unroll
  for (int k = 0; k < 4; ++k) {
    float f = vv[k];
    unsigned short h1 = f2bf(f);  float r1 = f  - bf2f(h1);
    unsigned short h2 = f2bf(r1); float r2 = r1 - bf2f(h2);
    unsigned short h3 = f2bf(r2);
    u1[k] = h1; u2[k] = h2; u3[k] = h3;
  }
  *(ushort4*)(p + i)         = make_ushort4(u1[0], u1[1], u1[2], u1[3]);
  *(ushort4*)(p + n + i)     = make_ushort4(u2[0], u2[1], u2[2], u2[3]);
  *(ushort4*)(p + 2*n + i)   = make_ushort4(u3[0], u3[1], u3[2], u3[3]);
}

// ======== multi-plane bf16 MFMA GEMM: C[M,N] = A[M,K] * B[N,K]^T ========
// NPROD=3: products (0,0),(0,1),(1,0) of the plane expansion — empirically
// indistinguishable from fp32 at this network's amplification (R4 post-mortem).
template <int NPROD>
__global__ __launch_bounds__(256) void gemm_mp(const unsigned short* __restrict__ Ap,
                                               const unsigned short* __restrict__ Bp,
                                               float* __restrict__ C,
                                               int M, int N, int K) {
  constexpr int NP    = (NPROD == 6) ? 3 : 2;
  constexpr int NCH   = NP * 2 * 512;
  constexpr int ITERS = NCH / 256;
  __shared__ unsigned short S[NP * 2 * 128 * 32];

  const int t  = threadIdx.x;
  const int w  = t >> 6;
  const int l  = t & 63;
  const int lm = l & 15;
  const int q8 = (l >> 4) << 3;
  const int m0 = blockIdx.y * 128;
  const int n0 = blockIdx.x * 128;
  const int wm = (w & 1) << 6;
  const int wn = (w >> 1) << 6;

  const unsigned short* src[ITERS];
  unsigned short* dst[ITERS];
#pragma unroll
  for (int it = 0; it < ITERS; ++it) {
    int c  = it * 256 + t;
    int p  = c >> 9;
    int wi = c & 511;
    int r  = wi >> 2;
    int kq = (wi & 3) << 3;
    const unsigned short* base = (p < NP)
        ? (Ap + (size_t)p * M * K + (size_t)(m0 + r) * K)
        : (Bp + (size_t)(p - NP) * N * K + (size_t)(n0 + r) * K);
    src[it] = base + kq;
    dst[it] = &S[(size_t)(it * 256 + (w << 6)) * 8];
  }

  f32x4 acc[4][4];
#pragma unroll
  for (int i = 0; i < 4; ++i)
#pragma unroll
    for (int j = 0; j < 4; ++j) acc[i][j] = (f32x4){0.f, 0.f, 0.f, 0.f};

  constexpr int PI[6] = {0, 0, 1, 0, 1, 2};
  constexpr int PJ[6] = {0, 1, 0, 2, 1, 0};

  for (int k0 = 0; k0 < K; k0 += 32) {
#pragma unroll
    for (int it = 0; it < ITERS; ++it) {
      __builtin_amdgcn_global_load_lds(
          (const __attribute__((address_space(1))) unsigned int*)src[it],
          (__attribute__((address_space(3))) unsigned int*)dst[it], 16, 0, 0);
      src[it] += 32;
    }
    __syncthreads();
#pragma unroll
    for (int pp = 0; pp < NPROD; ++pp) {
      const int pi = PI[pp], pj = PJ[pp];
      bf16x8 av[4], bv[4];
#pragma unroll
      for (int i = 0; i < 4; ++i)
        av[i] = *(const bf16x8*)&S[pi * 4096 + (wm + i * 16 + lm) * 32 + q8];
#pragma unroll
      for (int j = 0; j < 4; ++j)
        bv[j] = *(const bf16x8*)&S[(NP + pj) * 4096 + (wn + j * 16 + lm) * 32 + q8];
#pragma unroll
      for (int i = 0; i < 4; ++i)
#pragma unroll
        for (int j = 0; j < 4; ++j)
          acc[i][j] = __builtin_amdgcn_mfma_f32_16x16x32_bf16(av[i], bv[j], acc[i][j], 0, 0, 0);
    }
    __syncthreads();
  }

  const int row0 = (l >> 4) << 2;
#pragma unroll
  for (int i = 0; i < 4; ++i)
#pragma unroll
    for (int j = 0; j < 4; ++j)
#pragma unroll
      for (int r = 0; r < 4; ++r) {
        int m = m0 + wm + i * 16 + row0 + r;
        int n = n0 + wn + j * 16 + lm;
        C[(size_t)m * N + n] = acc[i][j][r];
      }
}

// ---------------- fp32 GEMM (kept for dt_proj, K=64) ----------------
#define TBM 128
#define TBN 128
#define TBK 16
__global__ __launch_bounds__(256) void gemm_nt(const float* __restrict__ A, int lda,
                                               const float* __restrict__ W,
                                               float* __restrict__ C,
                                               int M, int N, int K) {
  __shared__ float As[TBK][TBM];
  __shared__ float Ws[TBK][TBN];
  const int t  = threadIdx.x;
  const int tx = t & 15;
  const int ty = (t >> 4) & 15;
  const int m0 = blockIdx.y * TBM;
  const int n0 = blockIdx.x * TBN;

  float acc[8][8];
#pragma unroll
  for (int i = 0; i < 8; ++i)
#pragma unroll
    for (int j = 0; j < 8; ++j) acc[i][j] = 0.f;

  for (int k0 = 0; k0 < K; k0 += TBK) {
#pragma unroll
    for (int j = 0; j < 2; ++j) {
      int e  = t + j * 256;
      int r  = e >> 2;
      int cq = (e & 3) << 2;
      const float* ap = A + (size_t)(m0 + r) * lda + (k0 + cq);
      float4 v = *(const float4*)ap;
      As[cq+0][r] = v.x; As[cq+1][r] = v.y; As[cq+2][r] = v.z; As[cq+3][r] = v.w;
      int n = n0 + r;
      float4 w2;
      if (n < N) w2 = *(const float4*)(W + (size_t)n * K + (k0 + cq));
      else { w2.x = 0.f; w2.y = 0.f; w2.z = 0.f; w2.w = 0.f; }
      Ws[cq+0][r] = w2.x; Ws[cq+1][r] = w2.y; Ws[cq+2][r] = w2.z; Ws[cq+3][r] = w2.w;
    }
    __syncthreads();
#pragma unroll
    for (int kk = 0; kk < TBK; ++kk) {
      float a[8], b[8];
#pragma unroll
      for (int i = 0; i < 4; ++i) { a[i] = As[kk][ty*4 + i]; a[i+4] = As[kk][64 + ty*4 + i]; }
#pragma unroll
      for (int j = 0; j < 4; ++j) { b[j] = Ws[kk][tx*4 + j]; b[j+4] = Ws[kk][64 + tx*4 + j]; }
#pragma unroll
      for (int i = 0; i < 8; ++i)
#pragma unroll
        for (int j = 0; j < 8; ++j) acc[i][j] += a[i] * b[j];
    }
    __syncthreads();
  }
#pragma unroll
  for (int i = 0; i < 8; ++i) {
    int m = m0 + ((i < 4) ? (ty*4 + i) : (64 + ty*4 + (i - 4)));
#pragma unroll
    for (int jh = 0; jh < 2; ++jh) {
      int n = n0 + jh*64 + tx*4;
      if (n < N) {
        float4 v;
        v.x = acc[i][jh*4+0]; v.y = acc[i][jh*4+1];
        v.z = acc[i][jh*4+2]; v.w = acc[i][jh*4+3];
        *(float4*)(C + (size_t)m * N + n) = v;
      }
    }
  }
}

// ---------------- x_proj split-K: C[4096,96] = xc * Wx^T ----------------
#define XPN 96
__global__ __launch_bounds__(256) void xproj_part_k(const float* __restrict__ A,
                                                    const float* __restrict__ W,
                                                    float* __restrict__ Cp) {
  __shared__ float As[16][128];
  __shared__ float Ws[16][XPN];
  const int t  = threadIdx.x;
  const int tx = t & 15;
  const int ty = t >> 4;
  const int m0 = blockIdx.x * 128;
  const int kb = blockIdx.y * 256;
  float acc[8][6];
#pragma unroll
  for (int i = 0; i < 8; ++i)
#pragma unroll
    for (int j = 0; j < 6; ++j) acc[i][j] = 0.f;

  for (int k0 = kb; k0 < kb + 256; k0 += 16) {
#pragma unroll
    for (int e = t; e < 512; e += 256) {
      int r = e >> 2, cq = (e & 3) << 2;
      float4 v = *(const float4*)(A + (size_t)(m0 + r) * DI + k0 + cq);
      As[cq+0][r] = v.x; As[cq+1][r] = v.y; As[cq+2][r] = v.z; As[cq+3][r] = v.w;
    }
    for (int e = t; e < 384; e += 256) {
      int r = e >> 2, cq = (e & 3) << 2;
      float4 v = *(const float4*)(W + (size_t)r * DI + k0 + cq);
      Ws[cq+0][r] = v.x; Ws[cq+1][r] = v.y; Ws[cq+2][r] = v.z; Ws[cq+3][r] = v.w;
    }
    __syncthreads();
#pragma unroll
    for (int kk = 0; kk < 16; ++kk) {
      float a[8], b[6];
#pragma unroll
      for (int i = 0; i < 8; ++i) a[i] = As[kk][ty*8 + i];
#pragma unroll
      for (int j = 0; j < 6; ++j) b[j] = Ws[kk][tx*6 + j];
#pragma unroll
      for (int i = 0; i < 8; ++i)
#pragma unroll
        for (int j = 0; j < 6; ++j) acc[i][j] += a[i] * b[j];
    }
    __syncthreads();
  }
  float* cp = Cp + (size_t)blockIdx.y * MM * XPN;
#pragma unroll
  for (int i = 0; i < 8; ++i)
#pragma unroll
    for (int j = 0; j < 6; ++j)
      cp[(size_t)(m0 + ty*8 + i) * XPN + tx*6 + j] = acc[i][j];
}

__global__ __launch_bounds__(256) void xproj_red_k(const float* __restrict__ Cp,
                                                   float* __restrict__ o) {
  int i = blockIdx.x * 256 + threadIdx.x;
  float s = 0.f;
#pragma unroll
  for (int ks = 0; ks < 8; ++ks) s += Cp[(size_t)ks * (MM * XPN) + i];
  o[i] = s;
}

__device__ __forceinline__ float fast_silu(float x) {
  return x * __builtin_amdgcn_rcpf(1.f + exp2f(-LOG2E * x));
}

// ---------------- depthwise causal conv1d + SiLU ----------------
__global__ __launch_bounds__(256) void conv_silu_k(const float* __restrict__ xz,
                                                   const float* __restrict__ cw,
                                                   const float* __restrict__ cb,
                                                   float* __restrict__ xc) {
  int idx = blockIdx.x * 256 + threadIdx.x;
  int c  = idx & (DI - 1);
  int bl = idx >> 11;
  int l  = bl & (LL - 1);
  float acc = cb[c];
#pragma unroll
  for (int k = 0; k < DCONVK; ++k) {
    int ls = l - (DCONVK - 1) + k;
    if (ls >= 0)
      acc += xz[(size_t)(bl - (DCONVK - 1) + k) * (2*DI) + c] * cw[c*DCONVK + k];
  }
  xc[idx] = fast_silu(acc);
}

__global__ __launch_bounds__(256) void bias_softplus_k(float* __restrict__ delta,
                                                       const float* __restrict__ bdt) {
  int idx = blockIdx.x * 256 + threadIdx.x;
  int c = idx & (DI - 1);
  float x = delta[idx] + bdt[c];
  delta[idx] = fmaxf(x, 0.f) + log1pf(expf(-fabsf(x)));
}

// ======================= chunked selective scan (4 lanes x 4 states) ===
// Thread mapping: g = [c][ch][nq]; quad of lanes (nq=0..3) owns one channel,
// each lane holds 4 states in registers (B/C are float4 loads). Butterfly is
// 2 stages (width 4) instead of 4. CHK=32 chunks for TLP.
__global__ __launch_bounds__(256) void scan_pass1(const float* __restrict__ delta,
                                                  const float* __restrict__ xc,
                                                  const float* __restrict__ xdbl,
                                                  const float* __restrict__ A_log,
                                                  float* __restrict__ Hc,
                                                  float* __restrict__ Sdt) {
  const int g  = blockIdx.x * 256 + threadIdx.x;
  const int nq = g & 3;
  const int ch = (g >> 2) & (BD - 1);
  const int c  = g >> 14;              // BD*4 = 2^14
  const int b  = ch >> 11;
  const int d  = ch & (DI - 1);
  float4 al = *(const float4*)(A_log + (size_t)d * NST + nq * 4);
  const float Av0 = -expf(al.x) * LOG2E, Av1 = -expf(al.y) * LOG2E;
  const float Av2_ = -expf(al.z) * LOG2E, Av3 = -expf(al.w) * LOG2E;
  const size_t rowbase = (size_t)b * LL + (size_t)c * LC;
  float h0 = 0.f, h1 = 0.f, h2 = 0.f, h3 = 0.f, S = 0.f;

#define P1_SU 4
  float aD[P1_SU], aX[P1_SU]; float4 aB[P1_SU];
  float bD[P1_SU], bX[P1_SU]; float4 bB[P1_SU];

#define P1_LOAD(l0, D_, X_, B_)                                        \
  { _Pragma("unroll")                                                  \
    for (int u = 0; u < P1_SU; ++u) {                                  \
      size_t bl = rowbase + (l0) + u;                                  \
      D_[u] = delta[bl * DI + d];                                      \
      X_[u] = xc[bl * DI + d];                                         \
      B_[u] = *(const float4*)(xdbl + bl * 96 + DTRANK + nq * 4);      \
    } }

#define P1_COMP(D_, X_, B_)                                            \
  { _Pragma("unroll")                                                  \
    for (int u = 0; u < P1_SU; ++u) {                                  \
      float dt = D_[u], uB = dt * X_[u];                               \
      h0 = fmaf(exp2f(dt * Av0), h0, uB * B_[u].x);                    \
      h1 = fmaf(exp2f(dt * Av1), h1, uB * B_[u].y);                    \
      h2 = fmaf(exp2f(dt * Av2_), h2, uB * B_[u].z);                   \
      h3 = fmaf(exp2f(dt * Av3), h3, uB * B_[u].w);                    \
      S += dt;                                                         \
    } }

  P1_LOAD(0, aD, aX, aB);
  for (int l0 = 0; l0 < LC; l0 += 2 * P1_SU) {
    P1_LOAD(l0 + P1_SU, bD, bX, bB);
    P1_COMP(aD, aX, aB);
    if (l0 + 2 * P1_SU < LC) P1_LOAD(l0 + 2 * P1_SU, aD, aX, aB);
    P1_COMP(bD, bX, bB);
  }
#undef P1_LOAD
#undef P1_COMP
  size_t hi = ((size_t)c * BD + ch) * NST + nq * 4;
  float4 hv; hv.x = h0; hv.y = h1; hv.z = h2; hv.w = h3;
  *(float4*)(Hc + hi) = hv;
  if (nq == 0) Sdt[(size_t)c * BD + ch] = S;
}

// In-place: Hc[c] (chunk end-state, zero-init) is replaced by the chunk's
// true START state. Sequential over the 32 chunks per (ch,n).
__global__ __launch_bounds__(256) void scan_pass2(float* __restrict__ Hc,
                                                  const float* __restrict__ Sdt,
                                                  const float* __restrict__ A_log) {
  const int g  = blockIdx.x * 256 + threadIdx.x;   // BD*NST threads
  const int n  = g & (NST - 1);
  const int ch = g >> 4;
  const int d  = ch & (DI - 1);
  const float Av2 = -expf(A_log[d * NST + n]) * LOG2E;
  float Sv[CHK];
#pragma unroll
  for (int c = 0; c < CHK; ++c) Sv[c] = Sdt[(size_t)c * BD + ch];
  float h = 0.f;
  float tmp = Hc[(size_t)ch * NST + n];
#pragma unroll
  for (int c = 0; c < CHK; ++c) {
    size_t idx = ((size_t)c * BD + ch) * NST + n;
    float tnext = (c + 1 < CHK) ? Hc[((size_t)(c+1) * BD + ch) * NST + n] : 0.f;
    Hc[idx] = h;                                    // store start state
    h = fmaf(exp2f(Av2 * Sv[c]), h, tmp);
    tmp = tnext;
  }
}

__global__ __launch_bounds__(256) void scan_pass3(float* dy,  // in: delta, out: y
                                                  const float* __restrict__ xc,
                                                  const float* __restrict__ xdbl,
                                                  const float* __restrict__ A_log,
                                                  const float* __restrict__ xz,
                                                  const float* __restrict__ Dp,
                                                  const float* __restrict__ Hc) {
  const int g  = blockIdx.x * 256 + threadIdx.x;
  const int nq = g & 3;
  const int ch = (g >> 2) & (BD - 1);
  const int c  = g >> 14;
  const int b  = ch >> 11;
  const int d  = ch & (DI - 1);
  float4 al = *(const float4*)(A_log + (size_t)d * NST + nq * 4);
  const float Av0 = -expf(al.x) * LOG2E, Av1 = -expf(al.y) * LOG2E;
  const float Av2_ = -expf(al.z) * LOG2E, Av3 = -expf(al.w) * LOG2E;
  const float Dv = Dp[d];
  const size_t rowbase = (size_t)b * LL + (size_t)c * LC;
  float4 hv = *(const float4*)(Hc + ((size_t)c * BD + ch) * NST + nq * 4);
  float h0 = hv.x, h1 = hv.y, h2 = hv.z, h3 = hv.w;

#define P3_SU 2
  float aD[P3_SU], aX[P3_SU], aZ[P3_SU]; float4 aB[P3_SU], aC[P3_SU];
  float bD[P3_SU], bX[P3_SU], bZ[P3_SU]; float4 bB[P3_SU], bC[P3_SU];

#define P3_LOAD(l0, D_, X_, Z_, B_, C_)                                \
  { _Pragma("unroll")                                                  \
    for (int u = 0; u < P3_SU; ++u) {                                  \
      size_t bl = rowbase + (l0) + u;                                  \
      D_[u] = dy[bl * DI + d];                                         \
      X_[u] = xc[bl * DI + d];                                         \
      Z_[u] = xz[bl * (2*DI) + DI + d];                                \
      B_[u] = *(const float4*)(xdbl + bl * 96 + DTRANK + nq * 4);      \
      C_[u] = *(const float4*)(xdbl + bl * 96 + DTRANK + NST + nq * 4);\
    } }

#define P3_COMP(l0, D_, X_, Z_, B_, C_)                                \
  { _Pragma("unroll")                                                  \
    for (int u = 0; u < P3_SU; ++u) {                                  \
      float dt = D_[u], uB = dt * X_[u];                               \
      h0 = fmaf(exp2f(dt * Av0), h0, uB * B_[u].x);                    \
      h1 = fmaf(exp2f(dt * Av1), h1, uB * B_[u].y);                    \
      h2 = fmaf(exp2f(dt * Av2_), h2, uB * B_[u].z);                   \
      h3 = fmaf(exp2f(dt * Av3), h3, uB * B_[u].w);                    \
      float s = fmaf(h1, C_[u].y, h0 * C_[u].x);                       \
      float t2 = fmaf(h3, C_[u].w, h2 * C_[u].z);                      \
      s += t2;                                                         \
      s += __shfl_xor(s, 1, 4);                                        \
      s += __shfl_xor(s, 2, 4);                                        \
      float yv = (s + X_[u] * Dv) * fast_silu(Z_[u]);                  \
      if (nq == 0) dy[(rowbase + (l0) + u) * DI + d] = yv;             \
    } }

  P3_LOAD(0, aD, aX, aZ, aB, aC);
  for (int l0 = 0; l0 < LC; l0 += 2 * P3_SU) {
    P3_LOAD(l0 + P3_SU, bD, bX, bZ, bB, bC);
    P3_COMP(l0, aD, aX, aZ, aB, aC);
    if (l0 + 2 * P3_SU < LC) P3_LOAD(l0 + 2 * P3_SU, aD, aX, aZ, aB, aC);
    P3_COMP(l0 + P3_SU, bD, bX, bZ, bB, bC);
  }
#undef P3_LOAD
#undef P3_COMP
}

// ---------------- RMSNorm ----------------
__global__ __launch_bounds__(256) void rmsnorm_k(const float* __restrict__ x,
                                                 const float* __restrict__ w,
                                                 float* __restrict__ o) {
  int row = blockIdx.x;
  const float* xr = x + (size_t)row * DIMM;
  float s = 0.f;
  for (int i = threadIdx.x; i < DIMM; i += 256) { float v = xr[i]; s += v * v; }
#pragma unroll
  for (int off = 32; off > 0; off >>= 1) s += __shfl_xor(s, off, 64);
  __shared__ float red[4];
  if ((threadIdx.x & 63) == 0) red[threadIdx.x >> 6] = s;
  __syncthreads();
  float tot = red[0] + red[1] + red[2] + red[3];
  float scale = rsqrtf(tot * (1.0f / DIMM) + 1e-5f);
  for (int i = threadIdx.x; i < DIMM; i += 256)
    o[(size_t)row * DIMM + i] = xr[i] * scale * w[i];
}

extern "C" void kernel_launch(void* const* d_in, const int* in_sizes, int n_in,
                              void* d_out, int out_size, void* d_ws, size_t ws_size,
                              hipStream_t stream) {
  (void)in_sizes; (void)n_in; (void)out_size; (void)ws_size;
  const float* x_in    = (const float*)d_in[0];
  const float* Wi_all  = (const float*)d_in[1];
  const float* cw_all  = (const float*)d_in[2];
  const float* cb_all  = (const float*)d_in[3];
  const float* Wx_all  = (const float*)d_in[4];
  const float* Wdt_all = (const float*)d_in[5];
  const float* bdt_all = (const float*)d_in[6];
  const float* Alog_all= (const float*)d_in[7];
  const float* D_all   = (const float*)d_in[8];
  const float* Wo_all  = (const float*)d_in[9];
  const float* rw_all  = (const float*)d_in[10];
  float* out = (float*)d_out;

  float* ws    = (float*)d_ws;
  float* xz    = ws;                          // MM*2*DI  = 16777216 fl
  float* xc    = xz   + (size_t)MM * 2 * DI;  // MM*DI    =  8388608 fl
  float* xdbl  = xc   + (size_t)MM * DI;      // MM*96    =   393216 fl
  float* delta = xdbl + (size_t)MM * 96;      // MM*DI    =  8388608 fl
  float* xbuf  = delta+ (size_t)MM * DI;      // MM*DIMM  =  4194304 fl (16.8MB)
  float* outtmp = xc;

  // Aliased scratch (stream-ordered, regions provably dead when borrowed):
  unsigned short* xpl  = (unsigned short*)delta;
  unsigned short* wipl = (unsigned short*)xc;
  float*          Cp   = delta;
  unsigned short* ypl  = (unsigned short*)xz;
  unsigned short* wopl = (unsigned short*)xz + (size_t)3 * MM * DI;
  float* Hc  = xbuf;                              // CHK*BD*NST = 2097152 fl
  float* Sdt = Hc + (size_t)CHK * BD * NST;       // CHK*BD     =  131072 fl (8.9MB tot)

  const int EW_GRID = (MM * DI) / 256;
  const int SCAN_GRID = (CHK * BD * 4) / 256;     // 2048 blocks

  for (int i = 0; i < DEPTH; ++i) {
    const float* Wi   = Wi_all  + (size_t)i * (2*DI) * DIMM;
    const float* cw   = cw_all  + (size_t)i * DI * DCONVK;
    const float* cb   = cb_all  + (size_t)i * DI;
    const float* Wx   = Wx_all  + (size_t)i * 96 * DI;
    const float* Wdt  = Wdt_all + (size_t)i * DI * DTRANK;
    const float* bdt  = bdt_all + (size_t)i * DI;
    const float* Alog = Alog_all+ (size_t)i * DI * NST;
    const float* Dp   = D_all   + (size_t)i * DI;
    const float* Wo   = Wo_all  + (size_t)i * DIMM * DI;
    const float* rw   = rw_all  + (size_t)i * DIMM;
    const float* xin  = (i == 0) ? x_in : xbuf;
    float* xout = (i == DEPTH - 1) ? out : xbuf;

    // 1) split x and Wi into bf16 planes
    cvt3_k<<<(MM*DIMM)/1024, 256, 0, stream>>>(xin, xpl, (size_t)MM * DIMM);
    cvt3_k<<<((2*DI)*DIMM)/1024, 256, 0, stream>>>(Wi, wipl, (size_t)(2*DI) * DIMM);
    // 2) in_proj (MFMA multi-plane P3)
    gemm_mp<3><<<dim3((2*DI)/128, MM/128), 256, 0, stream>>>(xpl, wipl, xz, MM, 2*DI, DIMM);
    // 3) depthwise causal conv + silu -> xc
    conv_silu_k<<<EW_GRID, 256, 0, stream>>>(xz, cw, cb, xc);
    // 4) x_proj (split-K fp32)
    xproj_part_k<<<dim3(MM/128, 8), 256, 0, stream>>>(xc, Wx, Cp);
    xproj_red_k<<<(MM*XPN)/256, 256, 0, stream>>>(Cp, xdbl);
    // 5) dt_proj (fp32, K=64)
    gemm_nt<<<dim3(DI/TBN, MM/TBM), 256, 0, stream>>>(xdbl, 96, Wdt, delta, MM, DI, DTRANK);
    // 6) delta = softplus(delta + bdt)
    bias_softplus_k<<<EW_GRID, 256, 0, stream>>>(delta, bdt);
    // 7) chunked selective scan + D-skip + silu(z) gate; y overwrites delta
    scan_pass1<<<SCAN_GRID, 256, 0, stream>>>(delta, xc, xdbl, Alog, Hc, Sdt);
    scan_pass2<<<(BD*NST)/256, 256, 0, stream>>>(Hc, Sdt, Alog);
    scan_pass3<<<SCAN_GRID, 256, 0, stream>>>(delta, xc, xdbl, Alog, xz, Dp, Hc);
    // 8) split y and Wo into bf16 planes (xz dead now)
    cvt3_k<<<(MM*DI)/1024, 256, 0, stream>>>(delta, ypl, (size_t)MM * DI);
    cvt3_k<<<(DIMM*DI)/1024, 256, 0, stream>>>(Wo, wopl, (size_t)DIMM * DI);
    // 9) out_proj (MFMA multi-plane P3)
    gemm_mp<3><<<dim3(DIMM/128, MM/128), 256, 0, stream>>>(ypl, wopl, outtmp, MM, DIMM, DI);
    // 10) rmsnorm -> next x (or d_out)
    rmsnorm_k<<<MM, 256, 0, stream>>>(outtmp, rw, xout);
  }
}

// Round 6
// 4016.919 us; speedup vs baseline: 4.3146x; 1.0404x over previous
//
#include <hip/hip_runtime.h>
#include <cstddef>

// Problem constants (fixed by the reference)
#define DEPTH  8
#define DIMM   1024
#define DI     2048      // d_inner
#define NST    16        // d_state
#define DCONVK 4
#define DTRANK 64
#define BB     2
#define LL     2048
#define MM     (BB*LL)   // 4096 rows
#define BD     (BB*DI)   // 4096 channels
#define CHK    32        // scan chunks
#define LC     (LL/CHK)  // 64 timesteps per chunk
#define LOG2E  1.44269504088896f

typedef __attribute__((ext_vector_type(8))) short bf16x8;
typedef __attribute__((ext_vector_type(4))) float f32x4;

// ================= fp32 -> bf16 plane split helpers =================
__device__ __forceinline__ unsigned short f2bf(float f) {
  unsigned int u = __float_as_uint(f);
  unsigned int r = (u + 0x7fffu + ((u >> 16) & 1u)) >> 16;   // RNE
  return (unsigned short)r;
}
__device__ __forceinline__ float bf2f(unsigned short h) {
  return __uint_as_float(((unsigned int)h) << 16);
}

// x[n] fp32 -> 2 planes (hi, lo) at p[0..n), p[n..2n)
__global__ __launch_bounds__(256) void cvt2_k(const float* __restrict__ x,
                                              unsigned short* __restrict__ p,
                                              size_t n) {
  size_t i = ((size_t)blockIdx.x * 256 + threadIdx.x) * 4;
  float4 v = *(const float4*)(x + i);
  float vv[4] = {v.x, v.y, v.z, v.w};
  unsigned short u1[4], u2[4];
#pragma unroll
  for (int k = 0; k < 4; ++k) {
    unsigned short h1 = f2bf(vv[k]);
    u1[k] = h1;
    u2[k] = f2bf(vv[k] - bf2f(h1));
  }
  *(ushort4*)(p + i)     = make_ushort4(u1[0], u1[1], u1[2], u1[3]);
  *(ushort4*)(p + n + i) = make_ushort4(u2[0], u2[1], u2[2], u2[3]);
}

// ======== 3-product 2-plane bf16 MFMA GEMM: C[M,N] = A*B^T ========
// A,B as 2 bf16 planes each (lda = row stride in shorts, pstr = plane
// stride in shorts). TM=128: 4 waves as 2x2, each 64x64. TM=64: 4 waves
// as 1x4, each 64x32 (for skinny-N: 2 blocks/CU instead of 1).
// LDS chunk placement XOR-swizzled via the staging source mapping so
// fragment ds_read_b128 is exactly 2-way bank-aliased (free, m136).
template <int TM>
__global__ __launch_bounds__(256) void gemm_mp(
    const unsigned short* __restrict__ Ap, int lda_a, int pstr_a,
    const unsigned short* __restrict__ Bp, int lda_b, int pstr_b,
    float* __restrict__ C, int M, int N, int K) {
  constexpr int NP    = 2;
  constexpr int NSLOT = NP * (TM + 128) * 4;    // 16B chunks per K-tile
  constexpr int ITERS = NSLOT / 256;
  constexpr int NF    = (TM == 128) ? 4 : 2;    // N-fragments per wave
  __shared__ unsigned short S[NP * (TM + 128) * 32];

  const int t   = threadIdx.x;
  const int w   = t >> 6;
  const int l   = t & 63;
  const int lm  = l & 15;
  const int q8  = (l >> 4) << 3;
  const int qs  = q8 ^ (((lm >> 1) & 3) << 3);  // swizzled chunk offset
  const int m0  = blockIdx.y * TM;
  const int n0  = blockIdx.x * 128;
  const int wm  = (TM == 128) ? ((w & 1) << 6) : 0;
  const int wn  = (TM == 128) ? ((w >> 1) << 6) : (w << 5);

  const unsigned short* src[ITERS];
  unsigned short* dst[ITERS];
#pragma unroll
  for (int it = 0; it < ITERS; ++it) {
    int c = it * 256 + t;
    const unsigned short* base;
    int r, aslot;
    if (c < NP * TM * 4) {
      int p  = c / (TM * 4);
      int wi = c % (TM * 4);
      r = wi >> 2; aslot = wi & 3;
      base = Ap + (size_t)p * pstr_a + (size_t)(m0 + r) * lda_a;
    } else {
      int c2 = c - NP * TM * 4;
      int p  = c2 >> 9;
      int wi = c2 & 511;
      r = wi >> 2; aslot = wi & 3;
      base = Bp + (size_t)p * pstr_b + (size_t)(n0 + r) * lda_b;
    }
    int kq = (aslot ^ ((r >> 1) & 3)) << 3;     // swizzled source chunk
    src[it] = base + kq;
    dst[it] = &S[(size_t)(it * 256 + (w << 6)) * 8];
  }

  f32x4 acc[4][NF];
#pragma unroll
  for (int i = 0; i < 4; ++i)
#pragma unroll
    for (int j = 0; j < NF; ++j) acc[i][j] = (f32x4){0.f, 0.f, 0.f, 0.f};

  for (int k0 = 0; k0 < K; k0 += 32) {
#pragma unroll
    for (int it = 0; it < ITERS; ++it) {
      __builtin_amdgcn_global_load_lds(
          (const __attribute__((address_space(1))) unsigned int*)src[it],
          (__attribute__((address_space(3))) unsigned int*)dst[it], 16, 0, 0);
      src[it] += 32;
    }
    __syncthreads();
    // fragment reads (reused across the 3 plane-products)
    bf16x8 a0[4], aX[4], b0[NF];
#pragma unroll
    for (int i = 0; i < 4; ++i)
      a0[i] = *(const bf16x8*)&S[(wm + i * 16 + lm) * 32 + qs];
#pragma unroll
    for (int j = 0; j < NF; ++j)
      b0[j] = *(const bf16x8*)&S[NP * TM * 32 + (wn + j * 16 + lm) * 32 + qs];
#pragma unroll
    for (int i = 0; i < 4; ++i)
#pragma unroll
      for (int j = 0; j < NF; ++j)
        acc[i][j] = __builtin_amdgcn_mfma_f32_16x16x32_bf16(a0[i], b0[j], acc[i][j], 0, 0, 0);
#pragma unroll
    for (int j = 0; j < NF; ++j)   // B plane 1 (reuse aX as temp b1)
      aX[j & 3] = *(const bf16x8*)&S[NP * TM * 32 + 128 * 32 + (wn + j * 16 + lm) * 32 + qs];
#pragma unroll
    for (int i = 0; i < 4; ++i)
#pragma unroll
      for (int j = 0; j < NF; ++j)
        acc[i][j] = __builtin_amdgcn_mfma_f32_16x16x32_bf16(a0[i], aX[j], acc[i][j], 0, 0, 0);
#pragma unroll
    for (int i = 0; i < 4; ++i)    // A plane 1
      aX[i] = *(const bf16x8*)&S[TM * 32 + (wm + i * 16 + lm) * 32 + qs];
#pragma unroll
    for (int i = 0; i < 4; ++i)
#pragma unroll
      for (int j = 0; j < NF; ++j)
        acc[i][j] = __builtin_amdgcn_mfma_f32_16x16x32_bf16(aX[i], b0[j], acc[i][j], 0, 0, 0);
    __syncthreads();
  }

  // C/D layout: col = lane&15, row = (lane>>4)*4 + reg (m89/m91-verified)
  const int row0 = (l >> 4) << 2;
#pragma unroll
  for (int i = 0; i < 4; ++i)
#pragma unroll
    for (int j = 0; j < NF; ++j)
#pragma unroll
      for (int r = 0; r < 4; ++r) {
        int m = m0 + wm + i * 16 + row0 + r;
        int n = n0 + wn + j * 16 + lm;
        C[(size_t)m * N + n] = acc[i][j][r];
      }
}

// ------- dt_proj fused with bias + softplus: delta = sp(xdbl[:, :64]*Wdt^T + b) -------
__global__ __launch_bounds__(256) void dtproj_k(const float* __restrict__ A,   // [MM,96]
                                                const float* __restrict__ W,   // [DI,64]
                                                const float* __restrict__ bdt, // [DI]
                                                float* __restrict__ Cd) {      // [MM,DI]
  __shared__ float As[16][128];
  __shared__ float Ws[16][128];
  const int t  = threadIdx.x;
  const int tx = t & 15;
  const int ty = (t >> 4) & 15;
  const int m0 = blockIdx.y * 128;
  const int n0 = blockIdx.x * 128;

  float acc[8][8];
#pragma unroll
  for (int i = 0; i < 8; ++i)
#pragma unroll
    for (int j = 0; j < 8; ++j) acc[i][j] = 0.f;

  for (int k0 = 0; k0 < DTRANK; k0 += 16) {
#pragma unroll
    for (int jj = 0; jj < 2; ++jj) {
      int e  = t + jj * 256;
      int r  = e >> 2;
      int cq = (e & 3) << 2;
      float4 v = *(const float4*)(A + (size_t)(m0 + r) * 96 + (k0 + cq));
      As[cq+0][r] = v.x; As[cq+1][r] = v.y; As[cq+2][r] = v.z; As[cq+3][r] = v.w;
      float4 w2 = *(const float4*)(W + (size_t)(n0 + r) * DTRANK + (k0 + cq));
      Ws[cq+0][r] = w2.x; Ws[cq+1][r] = w2.y; Ws[cq+2][r] = w2.z; Ws[cq+3][r] = w2.w;
    }
    __syncthreads();
#pragma unroll
    for (int kk = 0; kk < 16; ++kk) {
      float a[8], b[8];
#pragma unroll
      for (int i = 0; i < 4; ++i) { a[i] = As[kk][ty*4 + i]; a[i+4] = As[kk][64 + ty*4 + i]; }
#pragma unroll
      for (int j = 0; j < 4; ++j) { b[j] = Ws[kk][tx*4 + j]; b[j+4] = Ws[kk][64 + tx*4 + j]; }
#pragma unroll
      for (int i = 0; i < 8; ++i)
#pragma unroll
        for (int j = 0; j < 8; ++j) acc[i][j] += a[i] * b[j];
    }
    __syncthreads();
  }
#pragma unroll
  for (int i = 0; i < 8; ++i) {
    int m = m0 + ((i < 4) ? (ty*4 + i) : (64 + ty*4 + (i - 4)));
#pragma unroll
    for (int jh = 0; jh < 2; ++jh) {
      int n = n0 + jh*64 + tx*4;
      float4 v;
      float* av = &acc[i][jh*4];
#pragma unroll
      for (int r = 0; r < 4; ++r) {
        float x = av[r] + bdt[n + r];
        ((float*)&v)[r] = fmaxf(x, 0.f) + log1pf(expf(-fabsf(x)));  // softplus
      }
      *(float4*)(Cd + (size_t)m * DI + n) = v;
    }
  }
}

// ---------------- x_proj split-K: C[4096,96] = xc * Wx^T ----------------
#define XPN 96
__global__ __launch_bounds__(256) void xproj_part_k(const float* __restrict__ A,
                                                    const float* __restrict__ W,
                                                    float* __restrict__ Cp) {
  __shared__ float As[16][128];
  __shared__ float Ws[16][XPN];
  const int t  = threadIdx.x;
  const int tx = t & 15;
  const int ty = t >> 4;
  const int m0 = blockIdx.x * 128;
  const int kb = blockIdx.y * 256;
  float acc[8][6];
#pragma unroll
  for (int i = 0; i < 8; ++i)
#pragma unroll
    for (int j = 0; j < 6; ++j) acc[i][j] = 0.f;

  for (int k0 = kb; k0 < kb + 256; k0 += 16) {
#pragma unroll
    for (int e = t; e < 512; e += 256) {
      int r = e >> 2, cq = (e & 3) << 2;
      float4 v = *(const float4*)(A + (size_t)(m0 + r) * DI + k0 + cq);
      As[cq+0][r] = v.x; As[cq+1][r] = v.y; As[cq+2][r] = v.z; As[cq+3][r] = v.w;
    }
    for (int e = t; e < 384; e += 256) {
      int r = e >> 2, cq = (e & 3) << 2;
      float4 v = *(const float4*)(W + (size_t)r * DI + k0 + cq);
      Ws[cq+0][r] = v.x; Ws[cq+1][r] = v.y; Ws[cq+2][r] = v.z; Ws[cq+3][r] = v.w;
    }
    __syncthreads();
#pragma unroll
    for (int kk = 0; kk < 16; ++kk) {
      float a[8], b[6];
#pragma unroll
      for (int i = 0; i < 8; ++i) a[i] = As[kk][ty*8 + i];
#pragma unroll
      for (int j = 0; j < 6; ++j) b[j] = Ws[kk][tx*6 + j];
#pragma unroll
      for (int i = 0; i < 8; ++i)
#pragma unroll
        for (int j = 0; j < 6; ++j) acc[i][j] += a[i] * b[j];
    }
    __syncthreads();
  }
  float* cp = Cp + (size_t)blockIdx.y * MM * XPN;
#pragma unroll
  for (int i = 0; i < 8; ++i)
#pragma unroll
    for (int j = 0; j < 6; ++j)
      cp[(size_t)(m0 + ty*8 + i) * XPN + tx*6 + j] = acc[i][j];
}

__global__ __launch_bounds__(256) void xproj_red_k(const float* __restrict__ Cp,
                                                   float* __restrict__ o) {
  int i = blockIdx.x * 256 + threadIdx.x;
  float s = 0.f;
#pragma unroll
  for (int ks = 0; ks < 8; ++ks) s += Cp[(size_t)ks * (MM * XPN) + i];
  o[i] = s;
}

__device__ __forceinline__ float fast_silu(float x) {
  return x * __builtin_amdgcn_rcpf(1.f + exp2f(-LOG2E * x));
}

// ---------------- depthwise causal conv1d + SiLU ----------------
__global__ __launch_bounds__(256) void conv_silu_k(const float* __restrict__ xz,
                                                   const float* __restrict__ cw,
                                                   const float* __restrict__ cb,
                                                   float* __restrict__ xc) {
  int idx = blockIdx.x * 256 + threadIdx.x;
  int c  = idx & (DI - 1);
  int bl = idx >> 11;
  int l  = bl & (LL - 1);
  float acc = cb[c];
#pragma unroll
  for (int k = 0; k < DCONVK; ++k) {
    int ls = l - (DCONVK - 1) + k;
    if (ls >= 0)
      acc += xz[(size_t)(bl - (DCONVK - 1) + k) * (2*DI) + c] * cw[c*DCONVK + k];
  }
  xc[idx] = fast_silu(acc);
}

// ======================= chunked selective scan (4 lanes x 4 states) ===
__global__ __launch_bounds__(256) void scan_pass1(const float* __restrict__ delta,
                                                  const float* __restrict__ xc,
                                                  const float* __restrict__ xdbl,
                                                  const float* __restrict__ A_log,
                                                  float* __restrict__ Hc,
                                                  float* __restrict__ Sdt) {
  const int g  = blockIdx.x * 256 + threadIdx.x;
  const int nq = g & 3;
  const int ch = (g >> 2) & (BD - 1);
  const int c  = g >> 14;
  const int b  = ch >> 11;
  const int d  = ch & (DI - 1);
  float4 al = *(const float4*)(A_log + (size_t)d * NST + nq * 4);
  const float Av0 = -expf(al.x) * LOG2E, Av1 = -expf(al.y) * LOG2E;
  const float Av2_ = -expf(al.z) * LOG2E, Av3 = -expf(al.w) * LOG2E;
  const size_t rowbase = (size_t)b * LL + (size_t)c * LC;
  float h0 = 0.f, h1 = 0.f, h2 = 0.f, h3 = 0.f, S = 0.f;

#define P1_SU 4
  float aD[P1_SU], aX[P1_SU]; float4 aB[P1_SU];
  float bD[P1_SU], bX[P1_SU]; float4 bB[P1_SU];

#define P1_LOAD(l0, D_, X_, B_)                                        \
  { _Pragma("unroll")                                                  \
    for (int u = 0; u < P1_SU; ++u) {                                  \
      size_t bl = rowbase + (l0) + u;                                  \
      D_[u] = delta[bl * DI + d];                                      \
      X_[u] = xc[bl * DI + d];                                         \
      B_[u] = *(const float4*)(xdbl + bl * 96 + DTRANK + nq * 4);      \
    } }

#define P1_COMP(D_, X_, B_)                                            \
  { _Pragma("unroll")                                                  \
    for (int u = 0; u < P1_SU; ++u) {                                  \
      float dt = D_[u], uB = dt * X_[u];                               \
      h0 = fmaf(exp2f(dt * Av0), h0, uB * B_[u].x);                    \
      h1 = fmaf(exp2f(dt * Av1), h1, uB * B_[u].y);                    \
      h2 = fmaf(exp2f(dt * Av2_), h2, uB * B_[u].z);                   \
      h3 = fmaf(exp2f(dt * Av3), h3, uB * B_[u].w);                    \
      S += dt;                                                         \
    } }

  P1_LOAD(0, aD, aX, aB);
  for (int l0 = 0; l0 < LC; l0 += 2 * P1_SU) {
    P1_LOAD(l0 + P1_SU, bD, bX, bB);
    P1_COMP(aD, aX, aB);
    if (l0 + 2 * P1_SU < LC) P1_LOAD(l0 + 2 * P1_SU, aD, aX, aB);
    P1_COMP(bD, bX, bB);
  }
#undef P1_LOAD
#undef P1_COMP
  size_t hi = ((size_t)c * BD + ch) * NST + nq * 4;
  float4 hv; hv.x = h0; hv.y = h1; hv.z = h2; hv.w = h3;
  *(float4*)(Hc + hi) = hv;
  if (nq == 0) Sdt[(size_t)c * BD + ch] = S;
}

__global__ __launch_bounds__(256) void scan_pass2(float* __restrict__ Hc,
                                                  const float* __restrict__ Sdt,
                                                  const float* __restrict__ A_log) {
  const int g  = blockIdx.x * 256 + threadIdx.x;
  const int n  = g & (NST - 1);
  const int ch = g >> 4;
  const int d  = ch & (DI - 1);
  const float Av2 = -expf(A_log[d * NST + n]) * LOG2E;
  float Sv[CHK];
#pragma unroll
  for (int c = 0; c < CHK; ++c) Sv[c] = Sdt[(size_t)c * BD + ch];
  float h = 0.f;
  float tmp = Hc[(size_t)ch * NST + n];
#pragma unroll
  for (int c = 0; c < CHK; ++c) {
    size_t idx = ((size_t)c * BD + ch) * NST + n;
    float tnext = (c + 1 < CHK) ? Hc[((size_t)(c+1) * BD + ch) * NST + n] : 0.f;
    Hc[idx] = h;
    h = fmaf(exp2f(Av2 * Sv[c]), h, tmp);
    tmp = tnext;
  }
}

// pass3: re-scan from true start state; emit gated y DIRECTLY AS 2 BF16
// PLANES into xz's xs-half (dead after conv): plane p of row bl at shorts
// [bl*8192 + p*2048 + d]. z-half (floats 2048..4095 of each row) untouched.
__global__ __launch_bounds__(256) void scan_pass3(const float* __restrict__ delta,
                                                  const float* __restrict__ xc,
                                                  const float* __restrict__ xdbl,
                                                  const float* __restrict__ A_log,
                                                  float* __restrict__ xzp,
                                                  const float* __restrict__ Dp,
                                                  const float* __restrict__ Hc) {
  const int g  = blockIdx.x * 256 + threadIdx.x;
  const int nq = g & 3;
  const int ch = (g >> 2) & (BD - 1);
  const int c  = g >> 14;
  const int b  = ch >> 11;
  const int d  = ch & (DI - 1);
  float4 al = *(const float4*)(A_log + (size_t)d * NST + nq * 4);
  const float Av0 = -expf(al.x) * LOG2E, Av1 = -expf(al.y) * LOG2E;
  const float Av2_ = -expf(al.z) * LOG2E, Av3 = -expf(al.w) * LOG2E;
  const float Dv = Dp[d];
  const size_t rowbase = (size_t)b * LL + (size_t)c * LC;
  float4 hv = *(const float4*)(Hc + ((size_t)c * BD + ch) * NST + nq * 4);
  float h0 = hv.x, h1 = hv.y, h2 = hv.z, h3 = hv.w;
  unsigned short* yp = (unsigned short*)xzp;

#define P3_SU 2
  float aD[P3_SU], aX[P3_SU], aZ[P3_SU]; float4 aB[P3_SU], aC[P3_SU];
  float bD[P3_SU], bX[P3_SU], bZ[P3_SU]; float4 bB[P3_SU], bC[P3_SU];

#define P3_LOAD(l0, D_, X_, Z_, B_, C_)                                \
  { _Pragma("unroll")                                                  \
    for (int u = 0; u < P3_SU; ++u) {                                  \
      size_t bl = rowbase + (l0) + u;                                  \
      D_[u] = delta[bl * DI + d];                                      \
      X_[u] = xc[bl * DI + d];                                         \
      Z_[u] = xzp[bl * (2*DI) + DI + d];                               \
      B_[u] = *(const float4*)(xdbl + bl * 96 + DTRANK + nq * 4);      \
      C_[u] = *(const float4*)(xdbl + bl * 96 + DTRANK + NST + nq * 4);\
    } }

#define P3_COMP(l0, D_, X_, Z_, B_, C_)                                \
  { _Pragma("unroll")                                                  \
    for (int u = 0; u < P3_SU; ++u) {                                  \
      float dt = D_[u], uB = dt * X_[u];                               \
      h0 = fmaf(exp2f(dt * Av0), h0, uB * B_[u].x);                    \
      h1 = fmaf(exp2f(dt * Av1), h1, uB * B_[u].y);                    \
      h2 = fmaf(exp2f(dt * Av2_), h2, uB * B_[u].z);                   \
      h3 = fmaf(exp2f(dt * Av3), h3, uB * B_[u].w);                    \
      float s = fmaf(h1, C_[u].y, h0 * C_[u].x);                       \
      float t2 = fmaf(h3, C_[u].w, h2 * C_[u].z);                      \
      s += t2;                                                         \
      s += __shfl_xor(s, 1, 4);                                        \
      s += __shfl_xor(s, 2, 4);                                        \
      if (nq == 0) {                                                   \
        float yv = (s + X_[u] * Dv) * fast_silu(Z_[u]);                \
        unsigned short y1 = f2bf(yv);                                  \
        unsigned short y2 = f2bf(yv - bf2f(y1));                       \
        size_t bl = rowbase + (l0) + u;                                \
        yp[bl * 8192 + d] = y1;                                        \
        yp[bl * 8192 + 2048 + d] = y2;                                 \
      }                                                                \
    } }

  P3_LOAD(0, aD, aX, aZ, aB, aC);
  for (int l0 = 0; l0 < LC; l0 += 2 * P3_SU) {
    P3_LOAD(l0 + P3_SU, bD, bX, bZ, bB, bC);
    P3_COMP(l0, aD, aX, aZ, aB, aC);
    if (l0 + 2 * P3_SU < LC) P3_LOAD(l0 + 2 * P3_SU, aD, aX, aZ, aB, aC);
    P3_COMP(l0 + P3_SU, bD, bX, bZ, bB, bC);
  }
#undef P3_LOAD
#undef P3_COMP
}

// ---------------- RMSNorm; emits bf16 planes (or fp32 on last layer) ----
template <bool PLANES>
__global__ __launch_bounds__(256) void rmsnorm_k(const float* __restrict__ x,
                                                 const float* __restrict__ w,
                                                 float* __restrict__ o,
                                                 unsigned short* __restrict__ op) {
  int row = blockIdx.x;
  const float* xr = x + (size_t)row * DIMM;
  float s = 0.f;
  for (int i = threadIdx.x; i < DIMM; i += 256) { float v = xr[i]; s += v * v; }
#pragma unroll
  for (int off = 32; off > 0; off >>= 1) s += __shfl_xor(s, off, 64);
  __shared__ float red[4];
  if ((threadIdx.x & 63) == 0) red[threadIdx.x >> 6] = s;
  __syncthreads();
  float tot = red[0] + red[1] + red[2] + red[3];
  float scale = rsqrtf(tot * (1.0f / DIMM) + 1e-5f);
  for (int i = threadIdx.x; i < DIMM; i += 256) {
    float v = xr[i] * scale * w[i];
    if (PLANES) {
      unsigned short h1 = f2bf(v);
      op[(size_t)row * DIMM + i] = h1;
      op[(size_t)MM * DIMM + (size_t)row * DIMM + i] = f2bf(v - bf2f(h1));
    } else {
      o[(size_t)row * DIMM + i] = v;
    }
  }
}

extern "C" void kernel_launch(void* const* d_in, const int* in_sizes, int n_in,
                              void* d_out, int out_size, void* d_ws, size_t ws_size,
                              hipStream_t stream) {
  (void)in_sizes; (void)n_in; (void)out_size; (void)ws_size;
  const float* x_in    = (const float*)d_in[0];
  const float* Wi_all  = (const float*)d_in[1];
  const float* cw_all  = (const float*)d_in[2];
  const float* cb_all  = (const float*)d_in[3];
  const float* Wx_all  = (const float*)d_in[4];
  const float* Wdt_all = (const float*)d_in[5];
  const float* bdt_all = (const float*)d_in[6];
  const float* Alog_all= (const float*)d_in[7];
  const float* D_all   = (const float*)d_in[8];
  const float* Wo_all  = (const float*)d_in[9];
  const float* rw_all  = (const float*)d_in[10];
  float* out = (float*)d_out;

  float* ws    = (float*)d_ws;
  float* xz    = ws;                          // MM*2*DI  = 16777216 fl (67MB)
  float* xc    = xz   + (size_t)MM * 2 * DI;  // MM*DI    =  8388608 fl (33.5MB)
  float* xdbl  = xc   + (size_t)MM * DI;      // MM*96    =   393216 fl
  float* delta = xdbl + (size_t)MM * 96;      // MM*DI    =  8388608 fl (33.5MB)
  float* xbuf  = delta+ (size_t)MM * DI;      // MM*DIMM  =  4194304 fl (16.8MB)
  float* outtmp = xc;                         // xc lower half (16.8MB)

  // Aliased scratch (stream-ordered; every borrow is of a provably-dead region):
  unsigned short* xpl  = (unsigned short*)delta;            // 2 planes x MM*DIMM (16.8MB)
  unsigned short* wipl = (unsigned short*)xc;               // 2 planes x (2DI)*DIMM (16.8MB)
  unsigned short* wopl = (unsigned short*)(xc + (size_t)4194304); // xc upper half (8.4MB)
  float*          Cp   = delta;                             // x_proj partials (12.6MB)
  float* Hc  = xbuf;                              // CHK*BD*NST = 2097152 fl
  float* Sdt = Hc + (size_t)CHK * BD * NST;       // CHK*BD     =  131072 fl

  const int EW_GRID = (MM * DI) / 256;
  const int SCAN_GRID = (CHK * BD * 4) / 256;     // 2048 blocks

  for (int i = 0; i < DEPTH; ++i) {
    const float* Wi   = Wi_all  + (size_t)i * (2*DI) * DIMM;
    const float* cw   = cw_all  + (size_t)i * DI * DCONVK;
    const float* cb   = cb_all  + (size_t)i * DI;
    const float* Wx   = Wx_all  + (size_t)i * 96 * DI;
    const float* Wdt  = Wdt_all + (size_t)i * DI * DTRANK;
    const float* bdt  = bdt_all + (size_t)i * DI;
    const float* Alog = Alog_all+ (size_t)i * DI * NST;
    const float* Dp   = D_all   + (size_t)i * DI;
    const float* Wo   = Wo_all  + (size_t)i * DIMM * DI;
    const float* rw   = rw_all  + (size_t)i * DIMM;

    // 1) x planes: layer 0 converts input; later layers get them from rmsnorm
    if (i == 0)
      cvt2_k<<<(MM*DIMM)/1024, 256, 0, stream>>>(x_in, xpl, (size_t)MM * DIMM);
    cvt2_k<<<((2*DI)*DIMM)/1024, 256, 0, stream>>>(Wi, wipl, (size_t)(2*DI) * DIMM);
    // 2) in_proj: xz = x * Wi^T (MFMA 3-product)
    gemm_mp<128><<<dim3((2*DI)/128, MM/128), 256, 0, stream>>>(
        xpl, DIMM, MM*DIMM, wipl, DIMM, (2*DI)*DIMM, xz, MM, 2*DI, DIMM);
    // 3) depthwise causal conv + silu -> xc
    conv_silu_k<<<EW_GRID, 256, 0, stream>>>(xz, cw, cb, xc);
    // 4) x_proj (split-K fp32)
    xproj_part_k<<<dim3(MM/128, 8), 256, 0, stream>>>(xc, Wx, Cp);
    xproj_red_k<<<(MM*XPN)/256, 256, 0, stream>>>(Cp, xdbl);
    // 5) dt_proj + bias + softplus -> delta
    dtproj_k<<<dim3(DI/128, MM/128), 256, 0, stream>>>(xdbl, Wdt, bdt, delta);
    // 6) chunked selective scan; pass3 emits gated y as bf16 planes into xz
    scan_pass1<<<SCAN_GRID, 256, 0, stream>>>(delta, xc, xdbl, Alog, Hc, Sdt);
    scan_pass2<<<(BD*NST)/256, 256, 0, stream>>>(Hc, Sdt, Alog);
    scan_pass3<<<SCAN_GRID, 256, 0, stream>>>(delta, xc, xdbl, Alog, xz, Dp, Hc);
    // 7) Wo planes into xc upper half (xc conv-data dead after pass3)
    cvt2_k<<<(DIMM*DI)/1024, 256, 0, stream>>>(Wo, wopl, (size_t)DIMM * DI);
    // 8) out_proj: outtmp = y * Wo^T (TM=64 tiles: 512 blocks)
    gemm_mp<64><<<dim3(DIMM/128, MM/64), 256, 0, stream>>>(
        (const unsigned short*)xz, 8192, 2048, wopl, DI, DIMM*DI,
        outtmp, MM, DIMM, DI);
    // 9) rmsnorm -> x planes for next layer (fp32 to d_out on last layer)
    if (i < DEPTH - 1)
      rmsnorm_k<true><<<MM, 256, 0, stream>>>(outtmp, rw, nullptr, xpl);
    else
      rmsnorm_k<false><<<MM, 256, 0, stream>>>(outtmp, rw, out, nullptr);
  }
}

// Round 7
// 3763.090 us; speedup vs baseline: 4.6056x; 1.0675x over previous
//
#include <hip/hip_runtime.h>
#include <cstddef>

// Problem constants (fixed by the reference)
#define DEPTH  8
#define DIMM   1024
#define DI     2048      // d_inner
#define NST    16        // d_state
#define DCONVK 4
#define DTRANK 64
#define BB     2
#define LL     2048
#define MM     (BB*LL)   // 4096 rows
#define BD     (BB*DI)   // 4096 channels
#define CHK    32        // scan chunks
#define LC     (LL/CHK)  // 64 timesteps per chunk
#define LOG2E  1.44269504088896f

typedef __attribute__((ext_vector_type(8))) short bf16x8;
typedef __attribute__((ext_vector_type(4))) float f32x4;

// ================= fp32 -> bf16 plane split helpers =================
__device__ __forceinline__ unsigned short f2bf(float f) {
  unsigned int u = __float_as_uint(f);
  unsigned int r = (u + 0x7fffu + ((u >> 16) & 1u)) >> 16;   // RNE
  return (unsigned short)r;
}
__device__ __forceinline__ float bf2f(unsigned short h) {
  return __uint_as_float(((unsigned int)h) << 16);
}

// x[n] fp32 -> 2 planes (hi, lo) at p[0..n), p[n..2n)
__global__ __launch_bounds__(256) void cvt2_k(const float* __restrict__ x,
                                              unsigned short* __restrict__ p,
                                              size_t n) {
  size_t i = ((size_t)blockIdx.x * 256 + threadIdx.x) * 4;
  float4 v = *(const float4*)(x + i);
  float vv[4] = {v.x, v.y, v.z, v.w};
  unsigned short u1[4], u2[4];
#pragma unroll
  for (int k = 0; k < 4; ++k) {
    unsigned short h1 = f2bf(vv[k]);
    u1[k] = h1;
    u2[k] = f2bf(vv[k] - bf2f(h1));
  }
  *(ushort4*)(p + i)     = make_ushort4(u1[0], u1[1], u1[2], u1[3]);
  *(ushort4*)(p + n + i) = make_ushort4(u2[0], u2[1], u2[2], u2[3]);
}

// ======== 3-product 2-plane bf16 MFMA GEMM: C[M,N] = A*B^T ========
// (unchanged from R6; XOR-swizzled LDS, fragment reuse across products)
template <int TM>
__global__ __launch_bounds__(256) void gemm_mp(
    const unsigned short* __restrict__ Ap, int lda_a, int pstr_a,
    const unsigned short* __restrict__ Bp, int lda_b, int pstr_b,
    float* __restrict__ C, int M, int N, int K) {
  constexpr int NP    = 2;
  constexpr int NSLOT = NP * (TM + 128) * 4;    // 16B chunks per K-tile
  constexpr int ITERS = NSLOT / 256;
  constexpr int NF    = (TM == 128) ? 4 : 2;    // N-fragments per wave
  __shared__ unsigned short S[NP * (TM + 128) * 32];

  const int t   = threadIdx.x;
  const int w   = t >> 6;
  const int l   = t & 63;
  const int lm  = l & 15;
  const int q8  = (l >> 4) << 3;
  const int qs  = q8 ^ (((lm >> 1) & 3) << 3);  // swizzled chunk offset
  const int m0  = blockIdx.y * TM;
  const int n0  = blockIdx.x * 128;
  const int wm  = (TM == 128) ? ((w & 1) << 6) : 0;
  const int wn  = (TM == 128) ? ((w >> 1) << 6) : (w << 5);

  const unsigned short* src[ITERS];
  unsigned short* dst[ITERS];
#pragma unroll
  for (int it = 0; it < ITERS; ++it) {
    int c = it * 256 + t;
    const unsigned short* base;
    int r, aslot;
    if (c < NP * TM * 4) {
      int p  = c / (TM * 4);
      int wi = c % (TM * 4);
      r = wi >> 2; aslot = wi & 3;
      base = Ap + (size_t)p * pstr_a + (size_t)(m0 + r) * lda_a;
    } else {
      int c2 = c - NP * TM * 4;
      int p  = c2 >> 9;
      int wi = c2 & 511;
      r = wi >> 2; aslot = wi & 3;
      base = Bp + (size_t)p * pstr_b + (size_t)(n0 + r) * lda_b;
    }
    int kq = (aslot ^ ((r >> 1) & 3)) << 3;     // swizzled source chunk
    src[it] = base + kq;
    dst[it] = &S[(size_t)(it * 256 + (w << 6)) * 8];
  }

  f32x4 acc[4][NF];
#pragma unroll
  for (int i = 0; i < 4; ++i)
#pragma unroll
    for (int j = 0; j < NF; ++j) acc[i][j] = (f32x4){0.f, 0.f, 0.f, 0.f};

  for (int k0 = 0; k0 < K; k0 += 32) {
#pragma unroll
    for (int it = 0; it < ITERS; ++it) {
      __builtin_amdgcn_global_load_lds(
          (const __attribute__((address_space(1))) unsigned int*)src[it],
          (__attribute__((address_space(3))) unsigned int*)dst[it], 16, 0, 0);
      src[it] += 32;
    }
    __syncthreads();
    bf16x8 a0[4], aX[4], b0[NF];
#pragma unroll
    for (int i = 0; i < 4; ++i)
      a0[i] = *(const bf16x8*)&S[(wm + i * 16 + lm) * 32 + qs];
#pragma unroll
    for (int j = 0; j < NF; ++j)
      b0[j] = *(const bf16x8*)&S[NP * TM * 32 + (wn + j * 16 + lm) * 32 + qs];
#pragma unroll
    for (int i = 0; i < 4; ++i)
#pragma unroll
      for (int j = 0; j < NF; ++j)
        acc[i][j] = __builtin_amdgcn_mfma_f32_16x16x32_bf16(a0[i], b0[j], acc[i][j], 0, 0, 0);
#pragma unroll
    for (int j = 0; j < NF; ++j)   // B plane 1
      aX[j & 3] = *(const bf16x8*)&S[NP * TM * 32 + 128 * 32 + (wn + j * 16 + lm) * 32 + qs];
#pragma unroll
    for (int i = 0; i < 4; ++i)
#pragma unroll
      for (int j = 0; j < NF; ++j)
        acc[i][j] = __builtin_amdgcn_mfma_f32_16x16x32_bf16(a0[i], aX[j], acc[i][j], 0, 0, 0);
#pragma unroll
    for (int i = 0; i < 4; ++i)    // A plane 1
      aX[i] = *(const bf16x8*)&S[TM * 32 + (wm + i * 16 + lm) * 32 + qs];
#pragma unroll
    for (int i = 0; i < 4; ++i)
#pragma unroll
      for (int j = 0; j < NF; ++j)
        acc[i][j] = __builtin_amdgcn_mfma_f32_16x16x32_bf16(aX[i], b0[j], acc[i][j], 0, 0, 0);
    __syncthreads();
  }

  const int row0 = (l >> 4) << 2;
#pragma unroll
  for (int i = 0; i < 4; ++i)
#pragma unroll
    for (int j = 0; j < NF; ++j)
#pragma unroll
      for (int r = 0; r < 4; ++r) {
        int m = m0 + wm + i * 16 + row0 + r;
        int n = n0 + wn + j * 16 + lm;
        C[(size_t)m * N + n] = acc[i][j][r];
      }
}

// ------- dt_proj via MFMA planes, fused bias+softplus -------
// delta[MM,DI] = softplus(dtpl[MM,64] * wdtpl[DI,64]^T + bdt). K=64: both
// K-tiles staged up-front (64KB LDS, one barrier), 96 MFMA per block.
__global__ __launch_bounds__(256) void dtproj_mp(const unsigned short* __restrict__ Ap,
                                                 const unsigned short* __restrict__ Bp,
                                                 const float* __restrict__ bdt,
                                                 float* __restrict__ Cd) {
  __shared__ unsigned short S[32768];   // 2 ktiles x (2 planes A + 2 planes B) x 128 x 32
  const int t  = threadIdx.x;
  const int w  = t >> 6;
  const int l  = t & 63;
  const int lm = l & 15;
  const int q8 = (l >> 4) << 3;
  const int qs = q8 ^ (((lm >> 1) & 3) << 3);
  const int m0 = blockIdx.y * 128;
  const int n0 = blockIdx.x * 128;
  const int wm = (w & 1) << 6;
  const int wn = (w >> 1) << 6;

#pragma unroll
  for (int it = 0; it < 16; ++it) {
    int c  = it * 256 + t;
    int kt = c >> 11;
    int c2 = c & 2047;
    const unsigned short* base;
    int r, aslot;
    if (c2 < 1024) {
      int p = c2 >> 9; int wi = c2 & 511; r = wi >> 2; aslot = wi & 3;
      base = Ap + (size_t)p * (MM * 64) + (size_t)(m0 + r) * 64;
    } else {
      int c3 = c2 - 1024;
      int p = c3 >> 9; int wi = c3 & 511; r = wi >> 2; aslot = wi & 3;
      base = Bp + (size_t)p * (DI * 64) + (size_t)(n0 + r) * 64;
    }
    int kq = (aslot ^ ((r >> 1) & 3)) << 3;
    __builtin_amdgcn_global_load_lds(
        (const __attribute__((address_space(1))) unsigned int*)(base + kt * 32 + kq),
        (__attribute__((address_space(3))) unsigned int*)&S[(size_t)(it * 256 + (w << 6)) * 8],
        16, 0, 0);
  }
  __syncthreads();

  f32x4 acc[4][4];
#pragma unroll
  for (int i = 0; i < 4; ++i)
#pragma unroll
    for (int j = 0; j < 4; ++j) acc[i][j] = (f32x4){0.f, 0.f, 0.f, 0.f};

#pragma unroll
  for (int kt = 0; kt < 2; ++kt) {
    const int RA = kt * 16384;          // A plane0 region (shorts)
    const int RB = kt * 16384 + 8192;   // B plane0 region
    bf16x8 a0[4], aX[4], b0[4];
#pragma unroll
    for (int i = 0; i < 4; ++i)
      a0[i] = *(const bf16x8*)&S[RA + (wm + i * 16 + lm) * 32 + qs];
#pragma unroll
    for (int j = 0; j < 4; ++j)
      b0[j] = *(const bf16x8*)&S[RB + (wn + j * 16 + lm) * 32 + qs];
#pragma unroll
    for (int i = 0; i < 4; ++i)
#pragma unroll
      for (int j = 0; j < 4; ++j)
        acc[i][j] = __builtin_amdgcn_mfma_f32_16x16x32_bf16(a0[i], b0[j], acc[i][j], 0, 0, 0);
#pragma unroll
    for (int j = 0; j < 4; ++j)        // B plane 1
      aX[j] = *(const bf16x8*)&S[RB + 4096 + (wn + j * 16 + lm) * 32 + qs];
#pragma unroll
    for (int i = 0; i < 4; ++i)
#pragma unroll
      for (int j = 0; j < 4; ++j)
        acc[i][j] = __builtin_amdgcn_mfma_f32_16x16x32_bf16(a0[i], aX[j], acc[i][j], 0, 0, 0);
#pragma unroll
    for (int i = 0; i < 4; ++i)        // A plane 1
      aX[i] = *(const bf16x8*)&S[RA + 4096 + (wm + i * 16 + lm) * 32 + qs];
#pragma unroll
    for (int i = 0; i < 4; ++i)
#pragma unroll
      for (int j = 0; j < 4; ++j)
        acc[i][j] = __builtin_amdgcn_mfma_f32_16x16x32_bf16(aX[i], b0[j], acc[i][j], 0, 0, 0);
  }

  const int row0 = (l >> 4) << 2;
#pragma unroll
  for (int j = 0; j < 4; ++j) {
    int n = n0 + wn + j * 16 + lm;
    float bv = bdt[n];
#pragma unroll
    for (int i = 0; i < 4; ++i)
#pragma unroll
      for (int r = 0; r < 4; ++r) {
        int m = m0 + wm + i * 16 + row0 + r;
        float x = acc[i][j][r] + bv;
        Cd[(size_t)m * DI + n] = fmaxf(x, 0.f) + log1pf(expf(-fabsf(x)));
      }
  }
}

// ---------------- x_proj split-K: C[4096,96] = xc * Wx^T ----------------
#define XPN 96
__global__ __launch_bounds__(256) void xproj_part_k(const float* __restrict__ A,
                                                    const float* __restrict__ W,
                                                    float* __restrict__ Cp) {
  __shared__ float As[16][128];
  __shared__ float Ws[16][XPN];
  const int t  = threadIdx.x;
  const int tx = t & 15;
  const int ty = t >> 4;
  const int m0 = blockIdx.x * 128;
  const int kb = blockIdx.y * 256;
  float acc[8][6];
#pragma unroll
  for (int i = 0; i < 8; ++i)
#pragma unroll
    for (int j = 0; j < 6; ++j) acc[i][j] = 0.f;

  for (int k0 = kb; k0 < kb + 256; k0 += 16) {
#pragma unroll
    for (int e = t; e < 512; e += 256) {
      int r = e >> 2, cq = (e & 3) << 2;
      float4 v = *(const float4*)(A + (size_t)(m0 + r) * DI + k0 + cq);
      As[cq+0][r] = v.x; As[cq+1][r] = v.y; As[cq+2][r] = v.z; As[cq+3][r] = v.w;
    }
    for (int e = t; e < 384; e += 256) {
      int r = e >> 2, cq = (e & 3) << 2;
      float4 v = *(const float4*)(W + (size_t)r * DI + k0 + cq);
      Ws[cq+0][r] = v.x; Ws[cq+1][r] = v.y; Ws[cq+2][r] = v.z; Ws[cq+3][r] = v.w;
    }
    __syncthreads();
#pragma unroll
    for (int kk = 0; kk < 16; ++kk) {
      float a[8], b[6];
#pragma unroll
      for (int i = 0; i < 8; ++i) a[i] = As[kk][ty*8 + i];
#pragma unroll
      for (int j = 0; j < 6; ++j) b[j] = Ws[kk][tx*6 + j];
#pragma unroll
      for (int i = 0; i < 8; ++i)
#pragma unroll
        for (int j = 0; j < 6; ++j) acc[i][j] += a[i] * b[j];
    }
    __syncthreads();
  }
  float* cp = Cp + (size_t)blockIdx.y * MM * XPN;
#pragma unroll
  for (int i = 0; i < 8; ++i)
#pragma unroll
    for (int j = 0; j < 6; ++j)
      cp[(size_t)(m0 + ty*8 + i) * XPN + tx*6 + j] = acc[i][j];
}

// reduce partials -> fp32 xdbl; dt columns (0..63) also emitted as 2 bf16 planes
__global__ __launch_bounds__(256) void xproj_red_k(const float* __restrict__ Cp,
                                                   float* __restrict__ o,
                                                   unsigned short* __restrict__ dtp) {
  int i = blockIdx.x * 256 + threadIdx.x;    // MM*96
  float s = 0.f;
#pragma unroll
  for (int ks = 0; ks < 8; ++ks) s += Cp[(size_t)ks * (MM * XPN) + i];
  o[i] = s;
  int m = i / 96, col = i - m * 96;
  if (col < DTRANK) {
    unsigned short h1 = f2bf(s);
    dtp[(size_t)m * DTRANK + col] = h1;
    dtp[(size_t)MM * DTRANK + (size_t)m * DTRANK + col] = f2bf(s - bf2f(h1));
  }
}

__device__ __forceinline__ float fast_silu(float x) {
  return x * __builtin_amdgcn_rcpf(1.f + exp2f(-LOG2E * x));
}

// ---------------- depthwise causal conv1d + SiLU ----------------
__global__ __launch_bounds__(256) void conv_silu_k(const float* __restrict__ xz,
                                                   const float* __restrict__ cw,
                                                   const float* __restrict__ cb,
                                                   float* __restrict__ xc) {
  int idx = blockIdx.x * 256 + threadIdx.x;
  int c  = idx & (DI - 1);
  int bl = idx >> 11;
  int l  = bl & (LL - 1);
  float acc = cb[c];
#pragma unroll
  for (int k = 0; k < DCONVK; ++k) {
    int ls = l - (DCONVK - 1) + k;
    if (ls >= 0)
      acc += xz[(size_t)(bl - (DCONVK - 1) + k) * (2*DI) + c] * cw[c*DCONVK + k];
  }
  xc[idx] = fast_silu(acc);
}

// ======================= chunked selective scan =======================
// Block = 64 channels x 1 chunk; xdbl B/C rows for the chunk staged once in
// LDS (broadcast reads), killing the 64x-redundant L2 traffic.
__global__ __launch_bounds__(256) void scan_pass1(const float* __restrict__ delta,
                                                  const float* __restrict__ xc,
                                                  const float* __restrict__ xdbl,
                                                  const float* __restrict__ A_log,
                                                  float* __restrict__ Hc,
                                                  float* __restrict__ Sdt) {
  const int t  = threadIdx.x;
  const int c  = blockIdx.x >> 6;
  const int g  = blockIdx.x & 63;
  const int q  = t >> 2;
  const int nq = t & 3;
  const int ch = g * 64 + q;
  const int b  = ch >> 11;
  const int d  = ch & (DI - 1);
  const size_t rowbase = (size_t)b * LL + (size_t)c * LC;

  __shared__ float Bs[LC * 16];   // 4KB: B rows of this chunk
  { int row = t >> 2, seg = t & 3;
    *(float4*)&Bs[row * 16 + seg * 4] =
        *(const float4*)(xdbl + (rowbase + row) * 96 + DTRANK + seg * 4);
  }
  __syncthreads();

  float4 al = *(const float4*)(A_log + (size_t)d * NST + nq * 4);
  const float Av0 = -expf(al.x) * LOG2E, Av1 = -expf(al.y) * LOG2E;
  const float Av2_ = -expf(al.z) * LOG2E, Av3 = -expf(al.w) * LOG2E;
  float h0 = 0.f, h1 = 0.f, h2 = 0.f, h3 = 0.f, S = 0.f;

#define P1_SU 4
  float aD[P1_SU], aX[P1_SU];
  float bD[P1_SU], bX[P1_SU];

#define P1_LOAD(l0, D_, X_)                                            \
  { _Pragma("unroll")                                                  \
    for (int u = 0; u < P1_SU; ++u) {                                  \
      size_t bl = rowbase + (l0) + u;                                  \
      D_[u] = delta[bl * DI + d];                                      \
      X_[u] = xc[bl * DI + d];                                         \
    } }

#define P1_COMP(l0, D_, X_)                                            \
  { _Pragma("unroll")                                                  \
    for (int u = 0; u < P1_SU; ++u) {                                  \
      float4 Bv = *(const float4*)&Bs[((l0) + u) * 16 + nq * 4];       \
      float dt = D_[u], uB = dt * X_[u];                               \
      h0 = fmaf(exp2f(dt * Av0), h0, uB * Bv.x);                       \
      h1 = fmaf(exp2f(dt * Av1), h1, uB * Bv.y);                       \
      h2 = fmaf(exp2f(dt * Av2_), h2, uB * Bv.z);                      \
      h3 = fmaf(exp2f(dt * Av3), h3, uB * Bv.w);                       \
      S += dt;                                                         \
    } }

  P1_LOAD(0, aD, aX);
  for (int l0 = 0; l0 < LC; l0 += 2 * P1_SU) {
    P1_LOAD(l0 + P1_SU, bD, bX);
    P1_COMP(l0, aD, aX);
    if (l0 + 2 * P1_SU < LC) P1_LOAD(l0 + 2 * P1_SU, aD, aX);
    P1_COMP(l0 + P1_SU, bD, bX);
  }
#undef P1_LOAD
#undef P1_COMP
  size_t hi = ((size_t)c * BD + ch) * NST + nq * 4;
  float4 hv; hv.x = h0; hv.y = h1; hv.z = h2; hv.w = h3;
  *(float4*)(Hc + hi) = hv;
  if (nq == 0) Sdt[(size_t)c * BD + ch] = S;
}

__global__ __launch_bounds__(256) void scan_pass2(float* __restrict__ Hc,
                                                  const float* __restrict__ Sdt,
                                                  const float* __restrict__ A_log) {
  const int g  = blockIdx.x * 256 + threadIdx.x;
  const int n  = g & (NST - 1);
  const int ch = g >> 4;
  const int d  = ch & (DI - 1);
  const float Av2 = -expf(A_log[d * NST + n]) * LOG2E;
  float Sv[CHK];
#pragma unroll
  for (int c = 0; c < CHK; ++c) Sv[c] = Sdt[(size_t)c * BD + ch];
  float h = 0.f;
  float tmp = Hc[(size_t)ch * NST + n];
#pragma unroll
  for (int c = 0; c < CHK; ++c) {
    size_t idx = ((size_t)c * BD + ch) * NST + n;
    float tnext = (c + 1 < CHK) ? Hc[((size_t)(c+1) * BD + ch) * NST + n] : 0.f;
    Hc[idx] = h;
    h = fmaf(exp2f(Av2 * Sv[c]), h, tmp);
    tmp = tnext;
  }
}

// pass3: re-scan from true start state; B/C staged in LDS; emits gated y as
// 2 bf16 planes into xz's xs-half (shorts [bl*8192 + p*2048 + d]).
__global__ __launch_bounds__(256) void scan_pass3(const float* __restrict__ delta,
                                                  const float* __restrict__ xc,
                                                  const float* __restrict__ xdbl,
                                                  const float* __restrict__ A_log,
                                                  float* __restrict__ xzp,
                                                  const float* __restrict__ Dp,
                                                  const float* __restrict__ Hc) {
  const int t  = threadIdx.x;
  const int c  = blockIdx.x >> 6;
  const int g  = blockIdx.x & 63;
  const int q  = t >> 2;
  const int nq = t & 3;
  const int ch = g * 64 + q;
  const int b  = ch >> 11;
  const int d  = ch & (DI - 1);
  const size_t rowbase = (size_t)b * LL + (size_t)c * LC;

  __shared__ float BCs[LC * 32];  // 8KB: B|C rows of this chunk
  {
#pragma unroll
    for (int e = t; e < 512; e += 256) {
      int row = e >> 3, seg = e & 7;
      *(float4*)&BCs[row * 32 + seg * 4] =
          *(const float4*)(xdbl + (rowbase + row) * 96 + DTRANK + seg * 4);
    }
  }
  __syncthreads();

  float4 al = *(const float4*)(A_log + (size_t)d * NST + nq * 4);
  const float Av0 = -expf(al.x) * LOG2E, Av1 = -expf(al.y) * LOG2E;
  const float Av2_ = -expf(al.z) * LOG2E, Av3 = -expf(al.w) * LOG2E;
  const float Dv = Dp[d];
  float4 hv = *(const float4*)(Hc + ((size_t)c * BD + ch) * NST + nq * 4);
  float h0 = hv.x, h1 = hv.y, h2 = hv.z, h3 = hv.w;
  unsigned short* yp = (unsigned short*)xzp;

#define P3_SU 2
  float aD[P3_SU], aX[P3_SU], aZ[P3_SU];
  float bD[P3_SU], bX[P3_SU], bZ[P3_SU];

#define P3_LOAD(l0, D_, X_, Z_)                                        \
  { _Pragma("unroll")                                                  \
    for (int u = 0; u < P3_SU; ++u) {                                  \
      size_t bl = rowbase + (l0) + u;                                  \
      D_[u] = delta[bl * DI + d];                                      \
      X_[u] = xc[bl * DI + d];                                         \
      Z_[u] = xzp[bl * (2*DI) + DI + d];                               \
    } }

#define P3_COMP(l0, D_, X_, Z_)                                        \
  { _Pragma("unroll")                                                  \
    for (int u = 0; u < P3_SU; ++u) {                                  \
      float4 Bv = *(const float4*)&BCs[((l0) + u) * 32 + nq * 4];      \
      float4 Cv = *(const float4*)&BCs[((l0) + u) * 32 + 16 + nq * 4]; \
      float dt = D_[u], uB = dt * X_[u];                               \
      h0 = fmaf(exp2f(dt * Av0), h0, uB * Bv.x);                       \
      h1 = fmaf(exp2f(dt * Av1), h1, uB * Bv.y);                       \
      h2 = fmaf(exp2f(dt * Av2_), h2, uB * Bv.z);                      \
      h3 = fmaf(exp2f(dt * Av3), h3, uB * Bv.w);                       \
      float s = fmaf(h1, Cv.y, h0 * Cv.x);                             \
      float t2 = fmaf(h3, Cv.w, h2 * Cv.z);                            \
      s += t2;                                                         \
      s += __shfl_xor(s, 1, 4);                                        \
      s += __shfl_xor(s, 2, 4);                                        \
      if (nq == 0) {                                                   \
        float yv = (s + X_[u] * Dv) * fast_silu(Z_[u]);                \
        unsigned short y1 = f2bf(yv);                                  \
        unsigned short y2 = f2bf(yv - bf2f(y1));                       \
        size_t bl = rowbase + (l0) + u;                                \
        yp[bl * 8192 + d] = y1;                                        \
        yp[bl * 8192 + 2048 + d] = y2;                                 \
      }                                                                \
    } }

  P3_LOAD(0, aD, aX, aZ);
  for (int l0 = 0; l0 < LC; l0 += 2 * P3_SU) {
    P3_LOAD(l0 + P3_SU, bD, bX, bZ);
    P3_COMP(l0, aD, aX, aZ);
    if (l0 + 2 * P3_SU < LC) P3_LOAD(l0 + 2 * P3_SU, aD, aX, aZ);
    P3_COMP(l0 + P3_SU, bD, bX, bZ);
  }
#undef P3_LOAD
#undef P3_COMP
}

// ---------------- RMSNorm; emits bf16 planes (or fp32 on last layer) ----
template <bool PLANES>
__global__ __launch_bounds__(256) void rmsnorm_k(const float* __restrict__ x,
                                                 const float* __restrict__ w,
                                                 float* __restrict__ o,
                                                 unsigned short* __restrict__ op) {
  int row = blockIdx.x;
  const float* xr = x + (size_t)row * DIMM;
  float s = 0.f;
  for (int i = threadIdx.x; i < DIMM; i += 256) { float v = xr[i]; s += v * v; }
#pragma unroll
  for (int off = 32; off > 0; off >>= 1) s += __shfl_xor(s, off, 64);
  __shared__ float red[4];
  if ((threadIdx.x & 63) == 0) red[threadIdx.x >> 6] = s;
  __syncthreads();
  float tot = red[0] + red[1] + red[2] + red[3];
  float scale = rsqrtf(tot * (1.0f / DIMM) + 1e-5f);
  for (int i = threadIdx.x; i < DIMM; i += 256) {
    float v = xr[i] * scale * w[i];
    if (PLANES) {
      unsigned short h1 = f2bf(v);
      op[(size_t)row * DIMM + i] = h1;
      op[(size_t)MM * DIMM + (size_t)row * DIMM + i] = f2bf(v - bf2f(h1));
    } else {
      o[(size_t)row * DIMM + i] = v;
    }
  }
}

extern "C" void kernel_launch(void* const* d_in, const int* in_sizes, int n_in,
                              void* d_out, int out_size, void* d_ws, size_t ws_size,
                              hipStream_t stream) {
  (void)in_sizes; (void)n_in; (void)out_size; (void)ws_size;
  const float* x_in    = (const float*)d_in[0];
  const float* Wi_all  = (const float*)d_in[1];
  const float* cw_all  = (const float*)d_in[2];
  const float* cb_all  = (const float*)d_in[3];
  const float* Wx_all  = (const float*)d_in[4];
  const float* Wdt_all = (const float*)d_in[5];
  const float* bdt_all = (const float*)d_in[6];
  const float* Alog_all= (const float*)d_in[7];
  const float* D_all   = (const float*)d_in[8];
  const float* Wo_all  = (const float*)d_in[9];
  const float* rw_all  = (const float*)d_in[10];
  float* out = (float*)d_out;

  float* ws    = (float*)d_ws;
  float* xz    = ws;                          // MM*2*DI  = 16777216 fl (67MB)
  float* xc    = xz   + (size_t)MM * 2 * DI;  // MM*DI    =  8388608 fl (33.5MB)
  float* xdbl  = xc   + (size_t)MM * DI;      // MM*96    =   393216 fl
  float* delta = xdbl + (size_t)MM * 96;      // MM*DI    =  8388608 fl (33.5MB)
  float* xbuf  = delta+ (size_t)MM * DI;      // MM*DIMM  =  4194304 fl (16.8MB)
  float* outtmp = xc;                         // xc lower half

  // Aliased scratch (stream-ordered; every borrow is of a provably-dead region):
  unsigned short* xpl  = (unsigned short*)delta;            // x planes (dead after in_proj)
  unsigned short* wipl = (unsigned short*)xc;               // Wi planes (dead after in_proj)
  unsigned short* wopl = (unsigned short*)(xc + (size_t)4194304); // xc upper half
  float*          Cp   = delta;                             // x_proj partials
  float* Hc   = xbuf;                                 // CHK*BD*NST = 2097152 fl
  float* Sdt  = Hc + (size_t)CHK * BD * NST;          // CHK*BD     =  131072 fl
  unsigned short* dtpl  = (unsigned short*)(xbuf + 2228224);  // 2 x MM*64 shorts (1MB)
  unsigned short* wdtpl = (unsigned short*)(xbuf + 2490368);  // 2 x DI*64 shorts (0.5MB)

  const int EW_GRID = (MM * DI) / 256;
  const int SCAN_GRID = CHK * 64;                     // [c][g] = 2048 blocks

  for (int i = 0; i < DEPTH; ++i) {
    const float* Wi   = Wi_all  + (size_t)i * (2*DI) * DIMM;
    const float* cw   = cw_all  + (size_t)i * DI * DCONVK;
    const float* cb   = cb_all  + (size_t)i * DI;
    const float* Wx   = Wx_all  + (size_t)i * 96 * DI;
    const float* Wdt  = Wdt_all + (size_t)i * DI * DTRANK;
    const float* bdt  = bdt_all + (size_t)i * DI;
    const float* Alog = Alog_all+ (size_t)i * DI * NST;
    const float* Dp   = D_all   + (size_t)i * DI;
    const float* Wo   = Wo_all  + (size_t)i * DIMM * DI;
    const float* rw   = rw_all  + (size_t)i * DIMM;

    // 1) x planes (layer 0 only; later layers get them from rmsnorm) + Wi planes
    if (i == 0)
      cvt2_k<<<(MM*DIMM)/1024, 256, 0, stream>>>(x_in, xpl, (size_t)MM * DIMM);
    cvt2_k<<<((2*DI)*DIMM)/1024, 256, 0, stream>>>(Wi, wipl, (size_t)(2*DI) * DIMM);
    // 2) in_proj: xz = x * Wi^T (MFMA 3-product)
    gemm_mp<128><<<dim3((2*DI)/128, MM/128), 256, 0, stream>>>(
        xpl, DIMM, MM*DIMM, wipl, DIMM, (2*DI)*DIMM, xz, MM, 2*DI, DIMM);
    // 3) depthwise causal conv + silu -> xc
    conv_silu_k<<<EW_GRID, 256, 0, stream>>>(xz, cw, cb, xc);
    // 4) x_proj (split-K fp32); reduce also emits dt planes
    xproj_part_k<<<dim3(MM/128, 8), 256, 0, stream>>>(xc, Wx, Cp);
    xproj_red_k<<<(MM*XPN)/256, 256, 0, stream>>>(Cp, xdbl, dtpl);
    cvt2_k<<<(DI*DTRANK)/1024, 256, 0, stream>>>(Wdt, wdtpl, (size_t)DI * DTRANK);
    // 5) dt_proj (MFMA planes) + bias + softplus -> delta
    dtproj_mp<<<dim3(DI/128, MM/128), 256, 0, stream>>>(dtpl, wdtpl, bdt, delta);
    // 6) chunked selective scan; pass3 emits gated y as bf16 planes into xz
    scan_pass1<<<SCAN_GRID, 256, 0, stream>>>(delta, xc, xdbl, Alog, Hc, Sdt);
    scan_pass2<<<(BD*NST)/256, 256, 0, stream>>>(Hc, Sdt, Alog);
    scan_pass3<<<SCAN_GRID, 256, 0, stream>>>(delta, xc, xdbl, Alog, xz, Dp, Hc);
    // 7) Wo planes into xc upper half (xc conv-data dead after pass3)
    cvt2_k<<<(DIMM*DI)/1024, 256, 0, stream>>>(Wo, wopl, (size_t)DIMM * DI);
    // 8) out_proj: outtmp = y * Wo^T (TM=64 tiles: 512 blocks)
    gemm_mp<64><<<dim3(DIMM/128, MM/64), 256, 0, stream>>>(
        (const unsigned short*)xz, 8192, 2048, wopl, DI, DIMM*DI,
        outtmp, MM, DIMM, DI);
    // 9) rmsnorm -> x planes for next layer (fp32 to d_out on last layer)
    if (i < DEPTH - 1)
      rmsnorm_k<true><<<MM, 256, 0, stream>>>(outtmp, rw, nullptr, xpl);
    else
      rmsnorm_k<false><<<MM, 256, 0, stream>>>(outtmp, rw, out, nullptr);
  }
}